// Round 13
// baseline (311.134 us; speedup 1.0000x reference)
//
#include <hip/hip_runtime.h>
#include <hip/hip_bf16.h>
#include <stdint.h>

// MozafariMNIST2018 forward. B=4096, T=15, HW=784, F1=500, F3=10.
// Output layout (float32, concatenated):
//   spk1 [4096*15*500] @ 0
//   thr1 [4096*15*500] @ 30720000
//   pot3 [4096*15*10]  @ 61440000
//   cls  [4096]        @ 62054400
//
// R13 = R12 with ONE controlled conv1 change: B weights single-f16
// (was hi/lo split) + near-threshold exact fp32 fixup from t0 nibbles.
// Halves MFMA + B-staging; LDS 80->48KB => 3 blocks/CU. A-staging stays
// t0-nibble (L2-resident, R12-proven). Fallback (small d_ws) = fp32-A
// single-f16+fixup (R9-proven correct).

typedef _Float16     f16x8 __attribute__((ext_vector_type(8)));
typedef float        f32x4 __attribute__((ext_vector_type(4)));
typedef unsigned int u32x4 __attribute__((ext_vector_type(4)));

typedef __attribute__((address_space(3))) char        lds_char_t;
typedef const __attribute__((address_space(1))) char  gbl_char_t;

#define GLL16(gsrc, ldst) \
  __builtin_amdgcn_global_load_lds((gbl_char_t*)(gsrc), (lds_char_t*)(ldst), 16, 0, 0)

#define CONV1_T   26.3424f
#define FIX_DELTA 0.05f
#define KDIM 784
#define F1   500

// ------------------------------------------------------------------
// k_t0 (R5/R12-verified): t0nib[b][p] (4-bit) = 15 - sum_t inp[b,t,p];
// pad pixels p>=784 -> 0xF. 400 B per batch row.
// ------------------------------------------------------------------
__global__ __launch_bounds__(256)
void k_t0(const float* __restrict__ inp, unsigned int* __restrict__ t0nib)
{
    const int gid = blockIdx.x * 256 + threadIdx.x;   // < 409600
    const int b   = gid / 100;
    const int p8  = gid % 100;
    if (p8 >= 98) { t0nib[gid] = 0xFFFFFFFFu; return; }

    const float* base = inp + (size_t)b * 11760 + p8 * 8;
    float cnt[8];
    #pragma unroll
    for (int e = 0; e < 8; ++e) cnt[e] = 0.f;
    #pragma unroll
    for (int t = 0; t < 15; ++t) {
        const f32x4 v0 = *(const f32x4*)(base + t * 784);
        const f32x4 v1 = *(const f32x4*)(base + t * 784 + 4);
        #pragma unroll
        for (int e = 0; e < 4; ++e) { cnt[e] += v0[e]; cnt[e + 4] += v1[e]; }
    }
    unsigned int d = 0;
    #pragma unroll
    for (int e = 0; e < 8; ++e) {
        const unsigned int t0 = 15u - (unsigned int)cnt[e];   // 0..14
        d |= (t0 & 15u) << (4 * e);
    }
    t0nib[gid] = d;
}

// rebuild 8 spike halfs from a t0 nibble dword: v[e] = (nib_e <= t)
__device__ __forceinline__
f16x8 rebuild_a(unsigned int d, int t)
{
    u32x4 br;
    #pragma unroll
    for (int h = 0; h < 4; ++h) {
        const unsigned int n0 = (d >> (8 * h))     & 15u;
        const unsigned int n1 = (d >> (8 * h + 4)) & 15u;
        br[h] = (n0 <= (unsigned)t ? 0x3C00u     : 0u)
              | (n1 <= (unsigned)t ? 0x3C000000u : 0u);
    }
    return __builtin_bit_cast(f16x8, br);
}

// exact fp32 recompute from t0 nibbles (R6-verified; same summation order
// as the reference-checked fix_dot)
__device__ __attribute__((noinline))
float fix_dot_t0(const unsigned char* __restrict__ nib,
                 const float* __restrict__ w, int t)
{
    float s0 = 0.f, s1 = 0.f, s2 = 0.f, s3 = 0.f;
    for (int k = 0; k < KDIM; k += 4) {
        const unsigned int b0 = nib[k >> 1];
        const unsigned int b1 = nib[(k >> 1) + 1];
        const float a0 = ((int)(b0 & 15u) <= t) ? 1.f : 0.f;
        const float a1 = ((int)(b0 >> 4)  <= t) ? 1.f : 0.f;
        const float a2 = ((int)(b1 & 15u) <= t) ? 1.f : 0.f;
        const float a3 = ((int)(b1 >> 4)  <= t) ? 1.f : 0.f;
        s0 = fmaf(a0, w[k],     s0);
        s1 = fmaf(a1, w[k + 1], s1);
        s2 = fmaf(a2, w[k + 2], s2);
        s3 = fmaf(a3, w[k + 3], s3);
    }
    return (s0 + s1) + (s2 + s3);
}

// exact fp32 recompute from fp32 input (fallback path; R4/R9-proven)
__device__ __attribute__((noinline))
float fix_dot(const float* __restrict__ a, const float* __restrict__ w)
{
    float s0 = 0.f, s1 = 0.f, s2 = 0.f, s3 = 0.f;
    for (int k = 0; k < KDIM; k += 4) {
        s0 = fmaf(a[k],     w[k],     s0);
        s1 = fmaf(a[k + 1], w[k + 1], s1);
        s2 = fmaf(a[k + 2], w[k + 2], s2);
        s3 = fmaf(a[k + 3], w[k + 3], s3);
    }
    return (s0 + s1) + (s2 + s3);
}

// ------------------------------------------------------------------
// k_prep (R9): w1 [500x784] fp32 -> single f16, conv1 LDS tile order.
// Tile (nb*25+ks) is 16384 B; chunk c (16B): nl=c>>2 (row), slot=c&3,
// k-chunk j = slot ^ ((nl>>1)&3) (XOR bank swizzle).
// ------------------------------------------------------------------
__global__ __launch_bounds__(256)
void k_prep(const float* __restrict__ w1, float* __restrict__ scratch)
{
    const int c = blockIdx.x * 256 + threadIdx.x;   // < 51200
    const int tile  = c >> 10;
    const int chunk = c & 1023;
    const int nb   = tile / 25;
    const int ks   = tile % 25;
    const int nl   = chunk >> 2;
    const int slot = chunk & 3;
    const int j    = slot ^ ((nl >> 1) & 3);
    const int k0   = ks * 32 + j * 8;
    const int ng   = nb * 256 + nl;

    f16x8 v;
    #pragma unroll
    for (int e = 0; e < 8; ++e) {
        const int kk = k0 + e;
        v[e] = (ng < F1 && kk < KDIM) ? (_Float16)w1[ng * KDIM + kk] : (_Float16)0.f;
    }
    *(f16x8*)((char*)scratch + (size_t)c * 16) = v;
}

// ------------------------------------------------------------------
// k_conv1_t0: A from t0 nibbles, B single-f16, near-threshold fixup.
// Tile BM=128, BN=256 (nb half), BK=32. 512 thr = 8 waves (2M x 4N).
// Double-buffered LDS (48KB -> 3 blocks/CU), 2-phase prefetch.
// ------------------------------------------------------------------
__global__ __launch_bounds__(512, 4)
void k_conv1_t0(const unsigned char* __restrict__ t0nib,
                const float* __restrict__ bsplit,
                const float* __restrict__ w1,
                float* __restrict__ spk1, float* __restrict__ thr1)
{
    __shared__ _Float16 sA[2][128 * 32];    // 2 x 8 KB
    __shared__ _Float16 sB[2][256 * 32];    // 2 x 16 KB

    const int tid  = threadIdx.x;
    const int lane = tid & 63;
    const int wid  = tid >> 6;     // 0..7
    const int wm   = wid >> 2;     // 0..1 (M)
    const int wn   = wid & 3;      // 0..3 (N)
    const int lr   = lane & 15;
    const int kg   = lane >> 4;

    // XCD pairing: bx and bx^8 share the same A tile on the same XCD.
    const int bx   = blockIdx.x;                    // 0..959
    const int nb   = (bx >> 3) & 1;
    const int mblk = ((bx >> 4) << 3) | (bx & 7);   // 0..479
    const long long rowBase = (long long)mblk * 128;

    // A staging role: thread -> (row sm, 8-wide k-chunk sk8)
    const int sm  = tid >> 2;      // 0..127
    const int sk8 = tid & 3;
    const int aWr = sm * 32 + (sk8 ^ ((sm >> 1) & 3)) * 8;
    const long long am = rowBase + sm;
    const int at = (int)(am % 15);
    const unsigned char* atp = t0nib + (am / 15) * 400 + sk8 * 4;  // + ks*16

    // B: GLL16 source (lane's 16B baked in); 2 x 1KB per wave per stage
    const char* gBsrc = (const char*)bsplit + (size_t)(nb * 25) * 16384
                      + (size_t)wid * 2048 + (size_t)lane * 16;

    f32x4 acc[4][4];
    #pragma unroll
    for (int i = 0; i < 4; ++i)
        #pragma unroll
        for (int j = 0; j < 4; ++j) acc[i][j] = {0.f, 0.f, 0.f, 0.f};

    int aOff[4], bOff[4];
    #pragma unroll
    for (int fm = 0; fm < 4; ++fm) {
        const int r = wm * 64 + fm * 16 + lr;
        aOff[fm] = r * 32 + (kg ^ ((r >> 1) & 3)) * 8;
    }
    #pragma unroll
    for (int fn = 0; fn < 4; ++fn) {
        const int n = wn * 64 + fn * 16 + lr;
        bOff[fn] = n * 32 + (kg ^ ((n >> 1) & 3)) * 8;
    }

    // ---- prologue: stage ks=0 into buffer 0
    {
        #pragma unroll
        for (int i = 0; i < 2; ++i)
            GLL16(gBsrc + i * 1024, (lds_char_t*)&sB[0][0] + wid * 2048 + i * 1024);
        const unsigned int d = *(const unsigned int*)(atp);
        *(f16x8*)&sA[0][aWr] = rebuild_a(d, at);
    }
    __syncthreads();

    for (int ks = 0; ks < 25; ++ks) {
        const int  cur = ks & 1;
        const bool pf  = (ks + 1 < 25);

        // ---- issue prefetch for tile ks+1 into buffer cur^1
        unsigned int dNext = 0;
        if (pf) {
            dNext = *(const unsigned int*)(atp + (ks + 1) * 16);
            const char*  src = gBsrc + (size_t)(ks + 1) * 16384;
            lds_char_t*  dst = (lds_char_t*)&sB[cur ^ 1][0] + wid * 2048;
            #pragma unroll
            for (int i = 0; i < 2; ++i)
                GLL16(src + i * 1024, dst + i * 1024);
        }

        // ---- compute tile ks from buffer cur
        const f16x8 a0 = *(const f16x8*)&sA[cur][aOff[0]];
        const f16x8 a1 = *(const f16x8*)&sA[cur][aOff[1]];
        const f16x8 a2 = *(const f16x8*)&sA[cur][aOff[2]];
        const f16x8 a3 = *(const f16x8*)&sA[cur][aOff[3]];
        #pragma unroll
        for (int fn = 0; fn < 4; ++fn) {
            const f16x8 b = *(const f16x8*)&sB[cur][bOff[fn]];
            acc[0][fn] = __builtin_amdgcn_mfma_f32_16x16x32_f16(a0, b, acc[0][fn], 0, 0, 0);
            acc[1][fn] = __builtin_amdgcn_mfma_f32_16x16x32_f16(a1, b, acc[1][fn], 0, 0, 0);
            acc[2][fn] = __builtin_amdgcn_mfma_f32_16x16x32_f16(a2, b, acc[2][fn], 0, 0, 0);
            acc[3][fn] = __builtin_amdgcn_mfma_f32_16x16x32_f16(a3, b, acc[3][fn], 0, 0, 0);
        }

        // ---- finish A prefetch: rebuild + LDS write into buffer cur^1
        if (pf)
            *(f16x8*)&sA[cur ^ 1][aWr] = rebuild_a(dNext, at);
        __syncthreads();
    }

    // ---- epilogue: fixup + fire. C/D: col=lane&15, row=(lane>>4)*4+r
    #pragma unroll
    for (int fm = 0; fm < 4; ++fm) {
        #pragma unroll
        for (int fn = 0; fn < 4; ++fn) {
            const int ng = nb * 256 + wn * 64 + fn * 16 + lr;
            if (ng < F1) {
                #pragma unroll
                for (int r = 0; r < 4; ++r) {
                    const long long m = rowBase + wm * 64 + fm * 16 + kg * 4 + r;
                    float p = acc[fm][fn][r];
                    if (__builtin_expect(fabsf(p - CONV1_T) < FIX_DELTA, 0))
                        p = fix_dot_t0(t0nib + (m / 15) * 400,
                                       w1 + (size_t)ng * KDIM, (int)(m % 15));
                    const bool fire = (p >= CONV1_T);
                    thr1[m * F1 + ng] = fire ? p : 0.f;
                    spk1[m * F1 + ng] = fire ? 1.f : 0.f;
                }
            }
        }
    }
}

// ------------------------------------------------------------------
// k_conv1_f32 (R9-proven fallback): fp32-A staging, single-f16 B, fixup.
// ------------------------------------------------------------------
__global__ __launch_bounds__(512, 4)
void k_conv1_f32(const float* __restrict__ inp, const float* __restrict__ bsplit,
                 const float* __restrict__ w1,
                 float* __restrict__ spk1, float* __restrict__ thr1)
{
    __shared__ _Float16 sA[2][128 * 32];
    __shared__ _Float16 sB[2][256 * 32];

    const int tid  = threadIdx.x;
    const int lane = tid & 63;
    const int wid  = tid >> 6;
    const int wm   = wid >> 2;
    const int wn   = wid & 3;
    const int lr   = lane & 15;
    const int kg   = lane >> 4;

    const int bx   = blockIdx.x;
    const int nb   = (bx >> 3) & 1;
    const int mblk = ((bx >> 4) << 3) | (bx & 7);
    const long long rowBase = (long long)mblk * 128;

    const int sm  = tid >> 2;
    const int sk8 = tid & 3;
    const int aWr = sm * 32 + (sk8 ^ ((sm >> 1) & 3)) * 8;
    const float* gA = inp + (rowBase + sm) * KDIM + sk8 * 8;

    const char* gBsrc = (const char*)bsplit + (size_t)(nb * 25) * 16384
                      + (size_t)wid * 2048 + (size_t)lane * 16;

    f32x4 acc[4][4];
    #pragma unroll
    for (int i = 0; i < 4; ++i)
        #pragma unroll
        for (int j = 0; j < 4; ++j) acc[i][j] = {0.f, 0.f, 0.f, 0.f};

    int aOff[4], bOff[4];
    #pragma unroll
    for (int fm = 0; fm < 4; ++fm) {
        const int r = wm * 64 + fm * 16 + lr;
        aOff[fm] = r * 32 + (kg ^ ((r >> 1) & 3)) * 8;
    }
    #pragma unroll
    for (int fn = 0; fn < 4; ++fn) {
        const int n = wn * 64 + fn * 16 + lr;
        bOff[fn] = n * 32 + (kg ^ ((n >> 1) & 3)) * 8;
    }

    {
        const f32x4 x0 = *(const f32x4*)(gA);
        const f32x4 x1 = *(const f32x4*)(gA + 4);
        #pragma unroll
        for (int i = 0; i < 2; ++i)
            GLL16(gBsrc + i * 1024, (lds_char_t*)&sB[0][0] + wid * 2048 + i * 1024);
        f16x8 v;
        #pragma unroll
        for (int e = 0; e < 4; ++e) { v[e] = (_Float16)x0[e]; v[e + 4] = (_Float16)x1[e]; }
        *(f16x8*)&sA[0][aWr] = v;
    }
    __syncthreads();

    for (int ks = 0; ks < 25; ++ks) {
        const int  cur = ks & 1;
        const bool pf  = (ks + 1 < 25);

        f32x4 x0 = {0.f, 0.f, 0.f, 0.f}, x1 = {0.f, 0.f, 0.f, 0.f};
        bool av = false;
        if (pf) {
            const int k0 = (ks + 1) * 32 + sk8 * 8;
            av = (k0 + 8 <= KDIM);
            if (av) {
                x0 = *(const f32x4*)(gA + (ks + 1) * 32);
                x1 = *(const f32x4*)(gA + (ks + 1) * 32 + 4);
            }
            const char*  src = gBsrc + (size_t)(ks + 1) * 16384;
            lds_char_t*  dst = (lds_char_t*)&sB[cur ^ 1][0] + wid * 2048;
            #pragma unroll
            for (int i = 0; i < 2; ++i)
                GLL16(src + i * 1024, dst + i * 1024);
        }

        const f16x8 a0 = *(const f16x8*)&sA[cur][aOff[0]];
        const f16x8 a1 = *(const f16x8*)&sA[cur][aOff[1]];
        const f16x8 a2 = *(const f16x8*)&sA[cur][aOff[2]];
        const f16x8 a3 = *(const f16x8*)&sA[cur][aOff[3]];
        #pragma unroll
        for (int fn = 0; fn < 4; ++fn) {
            const f16x8 b = *(const f16x8*)&sB[cur][bOff[fn]];
            acc[0][fn] = __builtin_amdgcn_mfma_f32_16x16x32_f16(a0, b, acc[0][fn], 0, 0, 0);
            acc[1][fn] = __builtin_amdgcn_mfma_f32_16x16x32_f16(a1, b, acc[1][fn], 0, 0, 0);
            acc[2][fn] = __builtin_amdgcn_mfma_f32_16x16x32_f16(a2, b, acc[2][fn], 0, 0, 0);
            acc[3][fn] = __builtin_amdgcn_mfma_f32_16x16x32_f16(a3, b, acc[3][fn], 0, 0, 0);
        }

        if (pf) {
            f16x8 v;
            #pragma unroll
            for (int e = 0; e < 4; ++e) {
                v[e]     = av ? (_Float16)x0[e] : (_Float16)0.f;
                v[e + 4] = av ? (_Float16)x1[e] : (_Float16)0.f;
            }
            *(f16x8*)&sA[cur ^ 1][aWr] = v;
        }
        __syncthreads();
    }

    #pragma unroll
    for (int fm = 0; fm < 4; ++fm) {
        #pragma unroll
        for (int fn = 0; fn < 4; ++fn) {
            const int ng = nb * 256 + wn * 64 + fn * 16 + lr;
            if (ng < F1) {
                #pragma unroll
                for (int r = 0; r < 4; ++r) {
                    const long long m = rowBase + wm * 64 + fm * 16 + kg * 4 + r;
                    float p = acc[fm][fn][r];
                    if (__builtin_expect(fabsf(p - CONV1_T) < FIX_DELTA, 0))
                        p = fix_dot(inp + m * KDIM, w1 + (size_t)ng * KDIM);
                    const bool fire = (p >= CONV1_T);
                    thr1[m * F1 + ng] = fire ? p : 0.f;
                    spk1[m * F1 + ng] = fire ? 1.f : 0.f;
                }
            }
        }
    }
}

// ------------------------------------------------------------------
// k_conv3 (R5-verified): pot3[row,g] = sum_f spk1[row,f]*w3[g,f] via
// 16x16x32 f16 MFMA. One wave = 16 rows.
// ------------------------------------------------------------------
__global__ __launch_bounds__(256)
void k_conv3(const float* __restrict__ spk1, const float* __restrict__ w3,
             float* __restrict__ pot3)
{
    const int tid  = threadIdx.x;
    const int lane = tid & 63;
    const int wid  = tid >> 6;
    const int gw   = blockIdx.x * 4 + wid;    // 0..3839
    const long long row0 = (long long)gw * 16;
    const int lr = lane & 15;
    const int kg = lane >> 4;
    const int n  = (lr < 10) ? lr : 0;

    const float* arow = spk1 + (row0 + lr) * F1;
    const float* brow = w3 + (size_t)n * F1;

    f32x4 acc = {0.f, 0.f, 0.f, 0.f};
    #pragma unroll
    for (int ks = 0; ks < 16; ++ks) {
        const int k0 = ks * 32 + kg * 8;
        f16x8 a, b;
        if (k0 + 8 <= F1) {
            const f32x4 a0 = *(const f32x4*)(arow + k0);
            const f32x4 a1 = *(const f32x4*)(arow + k0 + 4);
            const f32x4 b0 = *(const f32x4*)(brow + k0);
            const f32x4 b1 = *(const f32x4*)(brow + k0 + 4);
            #pragma unroll
            for (int e = 0; e < 4; ++e) {
                a[e] = (_Float16)a0[e]; a[e + 4] = (_Float16)a1[e];
                b[e] = (_Float16)b0[e]; b[e + 4] = (_Float16)b1[e];
            }
        } else {
            #pragma unroll
            for (int e = 0; e < 8; ++e) {
                const int k = k0 + e;
                a[e] = (k < F1) ? (_Float16)arow[k] : (_Float16)0.f;
                b[e] = (k < F1) ? (_Float16)brow[k] : (_Float16)0.f;
            }
        }
        acc = __builtin_amdgcn_mfma_f32_16x16x32_f16(a, b, acc, 0, 0, 0);
    }
    if (lr < 10) {
        #pragma unroll
        for (int r = 0; r < 4; ++r) {
            const long long m = row0 + kg * 4 + r;
            pot3[m * 10 + lr] = acc[r];
        }
    }
}

// ------------------------------------------------------------------
// k_winner: winner-take-all per batch, faithful to reference algebra.
// ------------------------------------------------------------------
__global__ __launch_bounds__(256)
void k_winner(const float* __restrict__ pot3, float* __restrict__ outCls, int nB)
{
    const int b = blockIdx.x * 256 + threadIdx.x;
    if (b >= nB) return;
    const float* p = pot3 + (long long)b * 150 + 140;   // t = 14 row

    float pv[10], s[10];
    float mv = 0.f;
    #pragma unroll
    for (int g = 0; g < 10; ++g) {
        const float v = p[g];
        pv[g] = v;
        s[g]  = (v > 0.f) ? 1.f : ((v < 0.f) ? -1.f : 0.f);
        mv = fmaxf(mv, s[g] * v);
    }
    const float vbig = mv * 15.f;
    float bm = -INFINITY; int bi = 0;
    #pragma unroll
    for (int g = 0; g < 10; ++g) {
        const float tot = s[g] * pv[g] + s[g] * vbig;
        if (tot > bm) { bm = tot; bi = g; }
    }
    outCls[b] = (bm != 0.f) ? (float)bi : -1.f;
}

// ------------------------------------------------------------------
extern "C" void kernel_launch(void* const* d_in, const int* in_sizes, int n_in,
                              void* d_out, int out_size, void* d_ws, size_t ws_size,
                              hipStream_t stream)
{
    const float* inp = (const float*)d_in[0];
    const float* w1  = (const float*)d_in[1];
    const float* w3  = (const float*)d_in[2];

    float* out  = (float*)d_out;
    float* spk1 = out;
    float* thr1 = out + 30720000LL;
    float* pot3 = out + 61440000LL;
    float* cls  = out + 62054400LL;

    if (ws_size >= 2457600) {
        // t0 path: w1f16 (819200 B) + t0nib (1638400 B) in d_ws
        float*        w1f16 = (float*)d_ws;
        unsigned int* t0nib = (unsigned int*)((char*)d_ws + 819200);
        k_prep    <<<200,  256, 0, stream>>>(w1, w1f16);
        k_t0      <<<1600, 256, 0, stream>>>(inp, t0nib);
        k_conv1_t0<<<960,  512, 0, stream>>>((const unsigned char*)t0nib, w1f16,
                                             w1, spk1, thr1);
    } else {
        // fallback: w1f16 borrows the pot3 region (conv3 overwrites after)
        float* scratch = pot3;
        k_prep     <<<200, 256, 0, stream>>>(w1, scratch);
        k_conv1_f32<<<960, 512, 0, stream>>>(inp, scratch, w1, spk1, thr1);
    }
    k_conv3 <<<960, 256, 0, stream>>>(spk1, w3, pot3);
    k_winner<<<16,  256, 0, stream>>>(pot3, cls, 4096);
}

// Round 14
// 208.174 us; speedup vs baseline: 1.4946x; 1.4946x over previous
//
#include <hip/hip_runtime.h>
#include <hip/hip_bf16.h>
#include <stdint.h>

// MozafariMNIST2018 forward. B=4096, T=15, HW=784, F1=500, F3=10.
// Output layout (float32, concatenated):
//   spk1 [4096*15*500] @ 0
//   thr1 [4096*15*500] @ 30720000
//   pot3 [4096*15*10]  @ 61440000
//   cls  [4096]        @ 62054400
//
// R14 = R12 revert (hi/lo conv1_t0, exact spikes, no fixup) + ONE change:
// k_t0 restructured for sequential HBM streaming (one block per batch,
// LDS-staged slab, conflict-free column sums). R13's single-f16 test
// confirmed (3rd time) that hi/lo's extra MFMA is free latency cover.

typedef _Float16     f16x8 __attribute__((ext_vector_type(8)));
typedef float        f32x4 __attribute__((ext_vector_type(4)));
typedef unsigned int u32x4 __attribute__((ext_vector_type(4)));

typedef __attribute__((address_space(3))) char        lds_char_t;
typedef const __attribute__((address_space(1))) char  gbl_char_t;

#define GLL16(gsrc, ldst) \
  __builtin_amdgcn_global_load_lds((gbl_char_t*)(gsrc), (lds_char_t*)(ldst), 16, 0, 0)

#define CONV1_T 26.3424f
#define KDIM 784
#define F1   500

// ------------------------------------------------------------------
// k_t0 (v2): one block per batch. Read [15][784] slab sequentially into
// LDS (47KB), per-thread 4-pixel column sums (lane stride 4 words ->
// conflict-free), shfl pair-merge, nibble-pack: t0 = 15 - sum_t spike.
// Pad pixels (p>=784) -> 0xF.
// ------------------------------------------------------------------
__global__ __launch_bounds__(256)
void k_t0(const float* __restrict__ inp, unsigned int* __restrict__ t0nib)
{
    __shared__ float sl[11760];
    const int b   = blockIdx.x;
    const int tid = threadIdx.x;

    const f32x4* src = (const f32x4*)(inp + (size_t)b * 11760);
    for (int i = tid; i < 2940; i += 256)
        *(f32x4*)&sl[i * 4] = src[i];
    __syncthreads();

    if (tid < 196) {
        const int p0 = tid * 4;
        float c0 = 0.f, c1 = 0.f, c2 = 0.f, c3 = 0.f;
        #pragma unroll
        for (int t = 0; t < 15; ++t) {
            const f32x4 v = *(const f32x4*)&sl[t * 784 + p0];
            c0 += v[0]; c1 += v[1]; c2 += v[2]; c3 += v[3];
        }
        // neighbor (tid^1) holds the other half of the 8-pixel dword
        const float n0 = __shfl_xor(c0, 1);
        const float n1 = __shfl_xor(c1, 1);
        const float n2 = __shfl_xor(c2, 1);
        const float n3 = __shfl_xor(c3, 1);
        if ((tid & 1) == 0) {
            const unsigned int t0a = 15u - (unsigned int)c0;
            const unsigned int t0b = 15u - (unsigned int)c1;
            const unsigned int t0c = 15u - (unsigned int)c2;
            const unsigned int t0d = 15u - (unsigned int)c3;
            const unsigned int t0e = 15u - (unsigned int)n0;
            const unsigned int t0f = 15u - (unsigned int)n1;
            const unsigned int t0g = 15u - (unsigned int)n2;
            const unsigned int t0h = 15u - (unsigned int)n3;
            const unsigned int d = (t0a & 15u) | ((t0b & 15u) << 4)
                                 | ((t0c & 15u) << 8)  | ((t0d & 15u) << 12)
                                 | ((t0e & 15u) << 16) | ((t0f & 15u) << 20)
                                 | ((t0g & 15u) << 24) | ((t0h & 15u) << 28);
            t0nib[b * 100 + (tid >> 1)] = d;
        }
    } else if (tid == 196) {
        t0nib[b * 100 + 98] = 0xFFFFFFFFu;
    } else if (tid == 197) {
        t0nib[b * 100 + 99] = 0xFFFFFFFFu;
    }
}

// rebuild 8 spike halfs from a t0 nibble dword: v[e] = (nib_e <= t)
__device__ __forceinline__
f16x8 rebuild_a(unsigned int d, int t)
{
    u32x4 br;
    #pragma unroll
    for (int h = 0; h < 4; ++h) {
        const unsigned int n0 = (d >> (8 * h))     & 15u;
        const unsigned int n1 = (d >> (8 * h + 4)) & 15u;
        br[h] = (n0 <= (unsigned)t ? 0x3C00u     : 0u)
              | (n1 <= (unsigned)t ? 0x3C000000u : 0u);
    }
    return __builtin_bit_cast(f16x8, br);
}

// ------------------------------------------------------------------
// k_prep (R3/R11/R12): split w1 [500x784] fp32 into f16 hi/lo, laid out
// exactly as the conv1 LDS tile bytes (GLL16-linear). Tile (nb*25+ks) is
// 32768 B: byte b -> part=b>>14 (0=hi,1=lo), nl=(b&16383)>>6,
// slot=(b>>4)&3, e=(b>>1)&7, k-chunk j = slot^((nl>>1)&3).
// ------------------------------------------------------------------
__global__ __launch_bounds__(256)
void k_prep(const float* __restrict__ w1, float* __restrict__ scratch)
{
    const int c = blockIdx.x * 256 + threadIdx.x;   // one 16B chunk each
    const int tile  = c >> 11;
    const int chunk = c & 2047;
    const int nb   = tile / 25;
    const int ks   = tile % 25;
    const int part = chunk >> 10;
    const int nl   = (chunk & 1023) >> 2;
    const int slot = chunk & 3;
    const int j    = slot ^ ((nl >> 1) & 3);
    const int k0   = ks * 32 + j * 8;
    const int ng   = nb * 256 + nl;

    f16x8 v;
    #pragma unroll
    for (int e = 0; e < 8; ++e) {
        const int kk = k0 + e;
        const float val = (ng < F1 && kk < KDIM) ? w1[ng * KDIM + kk] : 0.f;
        const _Float16 h = (_Float16)val;
        v[e] = part ? (_Float16)(val - (float)h) : h;
    }
    *(f16x8*)((char*)scratch + (size_t)c * 16) = v;
}

// ------------------------------------------------------------------
// k_conv1_t0 (R12 verbatim): A from t0 nibbles, B hi/lo split-f16.
// Tile BM=128, BN=256 (nb half), BK=32. 512 threads = 8 waves (2M x 4N).
// Double-buffered LDS (80KB) + 2-phase prefetch. Exact spikes, no fixup.
// ------------------------------------------------------------------
__global__ __launch_bounds__(512, 4)
void k_conv1_t0(const unsigned char* __restrict__ t0nib,
                const float* __restrict__ bsplit,
                float* __restrict__ spk1, float* __restrict__ thr1)
{
    __shared__ _Float16 sA[2][128 * 32];        // 2 x 8 KB
    __shared__ _Float16 sB[2][2 * 256 * 32];    // 2 x 32 KB (hi @0, lo @8192 halfs)

    const int tid  = threadIdx.x;
    const int lane = tid & 63;
    const int wid  = tid >> 6;     // 0..7
    const int wm   = wid >> 2;     // 0..1 (M)
    const int wn   = wid & 3;      // 0..3 (N)
    const int lr   = lane & 15;
    const int kg   = lane >> 4;

    // XCD pairing: bx and bx^8 share the same A tile on the same XCD.
    const int bx   = blockIdx.x;                    // 0..959
    const int nb   = (bx >> 3) & 1;
    const int mblk = ((bx >> 4) << 3) | (bx & 7);   // 0..479
    const long long rowBase = (long long)mblk * 128;

    // A staging role: thread -> (row sm, 8-wide k-chunk sk8)
    const int sm  = tid >> 2;      // 0..127
    const int sk8 = tid & 3;
    const int aWr = sm * 32 + (sk8 ^ ((sm >> 1) & 3)) * 8;
    const long long am = rowBase + sm;
    const int at = (int)(am % 15);
    const unsigned char* atp = t0nib + (am / 15) * 400 + sk8 * 4;  // + ks*16

    // B: global_load_lds source (lane's 16B baked in); 4 x 1KB per wave
    const char* gBsrc = (const char*)bsplit + (size_t)(nb * 25) * 32768
                      + (size_t)wid * 4096 + (size_t)lane * 16;

    f32x4 acc[4][4];
    #pragma unroll
    for (int i = 0; i < 4; ++i)
        #pragma unroll
        for (int j = 0; j < 4; ++j) acc[i][j] = {0.f, 0.f, 0.f, 0.f};

    int aOff[4], bOff[4];
    #pragma unroll
    for (int fm = 0; fm < 4; ++fm) {
        const int r = wm * 64 + fm * 16 + lr;
        aOff[fm] = r * 32 + (kg ^ ((r >> 1) & 3)) * 8;
    }
    #pragma unroll
    for (int fn = 0; fn < 4; ++fn) {
        const int n = wn * 64 + fn * 16 + lr;
        bOff[fn] = n * 32 + (kg ^ ((n >> 1) & 3)) * 8;
    }

    // ---- prologue: stage ks=0 into buffer 0
    {
        #pragma unroll
        for (int i = 0; i < 4; ++i)
            GLL16(gBsrc + i * 1024, (lds_char_t*)&sB[0][0] + wid * 4096 + i * 1024);
        const unsigned int d = *(const unsigned int*)(atp);
        *(f16x8*)&sA[0][aWr] = rebuild_a(d, at);
    }
    __syncthreads();

    for (int ks = 0; ks < 25; ++ks) {
        const int  cur = ks & 1;
        const bool pf  = (ks + 1 < 25);

        // ---- issue prefetch for tile ks+1 into buffer cur^1
        unsigned int dNext = 0;
        if (pf) {
            dNext = *(const unsigned int*)(atp + (ks + 1) * 16);
            const char*  src = gBsrc + (size_t)(ks + 1) * 32768;
            lds_char_t*  dst = (lds_char_t*)&sB[cur ^ 1][0] + wid * 4096;
            #pragma unroll
            for (int i = 0; i < 4; ++i)
                GLL16(src + i * 1024, dst + i * 1024);
        }

        // ---- compute tile ks from buffer cur
        const f16x8 a0 = *(const f16x8*)&sA[cur][aOff[0]];
        const f16x8 a1 = *(const f16x8*)&sA[cur][aOff[1]];
        const f16x8 a2 = *(const f16x8*)&sA[cur][aOff[2]];
        const f16x8 a3 = *(const f16x8*)&sA[cur][aOff[3]];
        #pragma unroll
        for (int fn = 0; fn < 4; ++fn) {
            const f16x8 bh = *(const f16x8*)&sB[cur][bOff[fn]];
            const f16x8 bl = *(const f16x8*)&sB[cur][8192 + bOff[fn]];
            acc[0][fn] = __builtin_amdgcn_mfma_f32_16x16x32_f16(a0, bh, acc[0][fn], 0, 0, 0);
            acc[0][fn] = __builtin_amdgcn_mfma_f32_16x16x32_f16(a0, bl, acc[0][fn], 0, 0, 0);
            acc[1][fn] = __builtin_amdgcn_mfma_f32_16x16x32_f16(a1, bh, acc[1][fn], 0, 0, 0);
            acc[1][fn] = __builtin_amdgcn_mfma_f32_16x16x32_f16(a1, bl, acc[1][fn], 0, 0, 0);
            acc[2][fn] = __builtin_amdgcn_mfma_f32_16x16x32_f16(a2, bh, acc[2][fn], 0, 0, 0);
            acc[2][fn] = __builtin_amdgcn_mfma_f32_16x16x32_f16(a2, bl, acc[2][fn], 0, 0, 0);
            acc[3][fn] = __builtin_amdgcn_mfma_f32_16x16x32_f16(a3, bh, acc[3][fn], 0, 0, 0);
            acc[3][fn] = __builtin_amdgcn_mfma_f32_16x16x32_f16(a3, bl, acc[3][fn], 0, 0, 0);
        }

        // ---- finish A prefetch: rebuild + LDS write into buffer cur^1
        if (pf)
            *(f16x8*)&sA[cur ^ 1][aWr] = rebuild_a(dNext, at);
        __syncthreads();
    }

    // ---- epilogue: fire. C/D layout: col = lane&15, row = (lane>>4)*4 + r
    #pragma unroll
    for (int fm = 0; fm < 4; ++fm) {
        #pragma unroll
        for (int fn = 0; fn < 4; ++fn) {
            const int ng = nb * 256 + wn * 64 + fn * 16 + lr;
            if (ng < F1) {
                #pragma unroll
                for (int r = 0; r < 4; ++r) {
                    const long long m = rowBase + wm * 64 + fm * 16 + kg * 4 + r;
                    const float p   = acc[fm][fn][r];
                    const bool fire = (p >= CONV1_T);
                    thr1[m * F1 + ng] = fire ? p : 0.f;
                    spk1[m * F1 + ng] = fire ? 1.f : 0.f;
                }
            }
        }
    }
}

// ------------------------------------------------------------------
// k_conv1_f32 (R11 verbatim; fallback when d_ws too small).
// ------------------------------------------------------------------
__global__ __launch_bounds__(512, 4)
void k_conv1_f32(const float* __restrict__ inp, const float* __restrict__ bsplit,
                 float* __restrict__ spk1, float* __restrict__ thr1)
{
    __shared__ _Float16 sA[2][128 * 32];
    __shared__ _Float16 sB[2][2 * 256 * 32];

    const int tid  = threadIdx.x;
    const int lane = tid & 63;
    const int wid  = tid >> 6;
    const int wm   = wid >> 2;
    const int wn   = wid & 3;
    const int lr   = lane & 15;
    const int kg   = lane >> 4;

    const int bx   = blockIdx.x;
    const int nb   = (bx >> 3) & 1;
    const int mblk = ((bx >> 4) << 3) | (bx & 7);
    const long long rowBase = (long long)mblk * 128;

    const int sm  = tid >> 2;
    const int sk8 = tid & 3;
    const int aWr = sm * 32 + (sk8 ^ ((sm >> 1) & 3)) * 8;
    const float* gA = inp + (rowBase + sm) * KDIM + sk8 * 8;

    const char* gBsrc = (const char*)bsplit + (size_t)(nb * 25) * 32768
                      + (size_t)wid * 4096 + (size_t)lane * 16;

    f32x4 acc[4][4];
    #pragma unroll
    for (int i = 0; i < 4; ++i)
        #pragma unroll
        for (int j = 0; j < 4; ++j) acc[i][j] = {0.f, 0.f, 0.f, 0.f};

    int aOff[4], bOff[4];
    #pragma unroll
    for (int fm = 0; fm < 4; ++fm) {
        const int r = wm * 64 + fm * 16 + lr;
        aOff[fm] = r * 32 + (kg ^ ((r >> 1) & 3)) * 8;
    }
    #pragma unroll
    for (int fn = 0; fn < 4; ++fn) {
        const int n = wn * 64 + fn * 16 + lr;
        bOff[fn] = n * 32 + (kg ^ ((n >> 1) & 3)) * 8;
    }

    {
        const f32x4 x0 = *(const f32x4*)(gA);
        const f32x4 x1 = *(const f32x4*)(gA + 4);
        #pragma unroll
        for (int i = 0; i < 4; ++i)
            GLL16(gBsrc + i * 1024, (lds_char_t*)&sB[0][0] + wid * 4096 + i * 1024);
        f16x8 v;
        #pragma unroll
        for (int e = 0; e < 4; ++e) { v[e] = (_Float16)x0[e]; v[e + 4] = (_Float16)x1[e]; }
        *(f16x8*)&sA[0][aWr] = v;
    }
    __syncthreads();

    for (int ks = 0; ks < 25; ++ks) {
        const int  cur = ks & 1;
        const bool pf  = (ks + 1 < 25);

        f32x4 x0 = {0.f, 0.f, 0.f, 0.f}, x1 = {0.f, 0.f, 0.f, 0.f};
        bool av = false;
        if (pf) {
            const int k0 = (ks + 1) * 32 + sk8 * 8;
            av = (k0 + 8 <= KDIM);
            if (av) {
                x0 = *(const f32x4*)(gA + (ks + 1) * 32);
                x1 = *(const f32x4*)(gA + (ks + 1) * 32 + 4);
            }
            const char*  src = gBsrc + (size_t)(ks + 1) * 32768;
            lds_char_t*  dst = (lds_char_t*)&sB[cur ^ 1][0] + wid * 4096;
            #pragma unroll
            for (int i = 0; i < 4; ++i)
                GLL16(src + i * 1024, dst + i * 1024);
        }

        const f16x8 a0 = *(const f16x8*)&sA[cur][aOff[0]];
        const f16x8 a1 = *(const f16x8*)&sA[cur][aOff[1]];
        const f16x8 a2 = *(const f16x8*)&sA[cur][aOff[2]];
        const f16x8 a3 = *(const f16x8*)&sA[cur][aOff[3]];
        #pragma unroll
        for (int fn = 0; fn < 4; ++fn) {
            const f16x8 bh = *(const f16x8*)&sB[cur][bOff[fn]];
            const f16x8 bl = *(const f16x8*)&sB[cur][8192 + bOff[fn]];
            acc[0][fn] = __builtin_amdgcn_mfma_f32_16x16x32_f16(a0, bh, acc[0][fn], 0, 0, 0);
            acc[0][fn] = __builtin_amdgcn_mfma_f32_16x16x32_f16(a0, bl, acc[0][fn], 0, 0, 0);
            acc[1][fn] = __builtin_amdgcn_mfma_f32_16x16x32_f16(a1, bh, acc[1][fn], 0, 0, 0);
            acc[1][fn] = __builtin_amdgcn_mfma_f32_16x16x32_f16(a1, bl, acc[1][fn], 0, 0, 0);
            acc[2][fn] = __builtin_amdgcn_mfma_f32_16x16x32_f16(a2, bh, acc[2][fn], 0, 0, 0);
            acc[2][fn] = __builtin_amdgcn_mfma_f32_16x16x32_f16(a2, bl, acc[2][fn], 0, 0, 0);
            acc[3][fn] = __builtin_amdgcn_mfma_f32_16x16x32_f16(a3, bh, acc[3][fn], 0, 0, 0);
            acc[3][fn] = __builtin_amdgcn_mfma_f32_16x16x32_f16(a3, bl, acc[3][fn], 0, 0, 0);
        }

        if (pf) {
            f16x8 v;
            #pragma unroll
            for (int e = 0; e < 4; ++e) {
                v[e]     = av ? (_Float16)x0[e] : (_Float16)0.f;
                v[e + 4] = av ? (_Float16)x1[e] : (_Float16)0.f;
            }
            *(f16x8*)&sA[cur ^ 1][aWr] = v;
        }
        __syncthreads();
    }

    #pragma unroll
    for (int fm = 0; fm < 4; ++fm) {
        #pragma unroll
        for (int fn = 0; fn < 4; ++fn) {
            const int ng = nb * 256 + wn * 64 + fn * 16 + lr;
            if (ng < F1) {
                #pragma unroll
                for (int r = 0; r < 4; ++r) {
                    const long long m = rowBase + wm * 64 + fm * 16 + kg * 4 + r;
                    const float p   = acc[fm][fn][r];
                    const bool fire = (p >= CONV1_T);
                    thr1[m * F1 + ng] = fire ? p : 0.f;
                    spk1[m * F1 + ng] = fire ? 1.f : 0.f;
                }
            }
        }
    }
}

// ------------------------------------------------------------------
// k_conv3 (R5-verified): pot3[row,g] = sum_f spk1[row,f]*w3[g,f] via
// 16x16x32 f16 MFMA. One wave = 16 rows.
// ------------------------------------------------------------------
__global__ __launch_bounds__(256)
void k_conv3(const float* __restrict__ spk1, const float* __restrict__ w3,
             float* __restrict__ pot3)
{
    const int tid  = threadIdx.x;
    const int lane = tid & 63;
    const int wid  = tid >> 6;
    const int gw   = blockIdx.x * 4 + wid;    // 0..3839
    const long long row0 = (long long)gw * 16;
    const int lr = lane & 15;
    const int kg = lane >> 4;
    const int n  = (lr < 10) ? lr : 0;

    const float* arow = spk1 + (row0 + lr) * F1;
    const float* brow = w3 + (size_t)n * F1;

    f32x4 acc = {0.f, 0.f, 0.f, 0.f};
    #pragma unroll
    for (int ks = 0; ks < 16; ++ks) {
        const int k0 = ks * 32 + kg * 8;
        f16x8 a, b;
        if (k0 + 8 <= F1) {
            const f32x4 a0 = *(const f32x4*)(arow + k0);
            const f32x4 a1 = *(const f32x4*)(arow + k0 + 4);
            const f32x4 b0 = *(const f32x4*)(brow + k0);
            const f32x4 b1 = *(const f32x4*)(brow + k0 + 4);
            #pragma unroll
            for (int e = 0; e < 4; ++e) {
                a[e] = (_Float16)a0[e]; a[e + 4] = (_Float16)a1[e];
                b[e] = (_Float16)b0[e]; b[e + 4] = (_Float16)b1[e];
            }
        } else {
            #pragma unroll
            for (int e = 0; e < 8; ++e) {
                const int k = k0 + e;
                a[e] = (k < F1) ? (_Float16)arow[k] : (_Float16)0.f;
                b[e] = (k < F1) ? (_Float16)brow[k] : (_Float16)0.f;
            }
        }
        acc = __builtin_amdgcn_mfma_f32_16x16x32_f16(a, b, acc, 0, 0, 0);
    }
    if (lr < 10) {
        #pragma unroll
        for (int r = 0; r < 4; ++r) {
            const long long m = row0 + kg * 4 + r;
            pot3[m * 10 + lr] = acc[r];
        }
    }
}

// ------------------------------------------------------------------
// k_winner: winner-take-all per batch, faithful to reference algebra.
// ------------------------------------------------------------------
__global__ __launch_bounds__(256)
void k_winner(const float* __restrict__ pot3, float* __restrict__ outCls, int nB)
{
    const int b = blockIdx.x * 256 + threadIdx.x;
    if (b >= nB) return;
    const float* p = pot3 + (long long)b * 150 + 140;   // t = 14 row

    float pv[10], s[10];
    float mv = 0.f;
    #pragma unroll
    for (int g = 0; g < 10; ++g) {
        const float v = p[g];
        pv[g] = v;
        s[g]  = (v > 0.f) ? 1.f : ((v < 0.f) ? -1.f : 0.f);
        mv = fmaxf(mv, s[g] * v);
    }
    const float vbig = mv * 15.f;
    float bm = -INFINITY; int bi = 0;
    #pragma unroll
    for (int g = 0; g < 10; ++g) {
        const float tot = s[g] * pv[g] + s[g] * vbig;
        if (tot > bm) { bm = tot; bi = g; }
    }
    outCls[b] = (bm != 0.f) ? (float)bi : -1.f;
}

// ------------------------------------------------------------------
extern "C" void kernel_launch(void* const* d_in, const int* in_sizes, int n_in,
                              void* d_out, int out_size, void* d_ws, size_t ws_size,
                              hipStream_t stream)
{
    const float* inp = (const float*)d_in[0];
    const float* w1  = (const float*)d_in[1];
    const float* w3  = (const float*)d_in[2];

    float* out  = (float*)d_out;
    float* spk1 = out;
    float* thr1 = out + 30720000LL;
    float* pot3 = out + 61440000LL;
    float* cls  = out + 62054400LL;

    if (ws_size >= 3276800) {
        // t0 path: w1split (1638400 B) + t0nib (1638400 B) in d_ws
        float*        w1split = (float*)d_ws;
        unsigned int* t0nib   = (unsigned int*)((char*)d_ws + 1638400);
        k_prep    <<<400,  256, 0, stream>>>(w1, w1split);
        k_t0      <<<4096, 256, 0, stream>>>(inp, t0nib);
        k_conv1_t0<<<960,  512, 0, stream>>>((const unsigned char*)t0nib, w1split,
                                             spk1, thr1);
    } else {
        // R11-exact fallback: w1split borrows the pot3 region
        float* scratch = pot3;
        k_prep     <<<400, 256, 0, stream>>>(w1, scratch);
        k_conv1_f32<<<960, 512, 0, stream>>>(inp, scratch, spk1, thr1);
    }
    k_conv3 <<<960, 256, 0, stream>>>(spk1, w3, pot3);
    k_winner<<<16,  256, 0, stream>>>(pot3, cls, 4096);
}

// Round 15
// 187.640 us; speedup vs baseline: 1.6581x; 1.1094x over previous
//
#include <hip/hip_runtime.h>
#include <hip/hip_bf16.h>
#include <stdint.h>

// MozafariMNIST2018 forward. B=4096, T=15, HW=784, F1=500, F3=10.
// Output layout (float32, concatenated):
//   spk1 [4096*15*500] @ 0
//   thr1 [4096*15*500] @ 30720000
//   pot3 [4096*15*10]  @ 61440000
//   cls  [4096]        @ 62054400
//
// R15 = R12 (best measured: 205.8us) + conv3 FUSED into conv1's epilogue:
// spike tile -> swizzled LDS -> 8 MFMA/wave vs f16 w3 -> atomicAdd pot3
// (exactly 2 contributors/element, float add commutative => deterministic).
// Saves the separate conv3 kernel and its 123MB spk1 re-read.

typedef _Float16     f16x8 __attribute__((ext_vector_type(8)));
typedef float        f32x4 __attribute__((ext_vector_type(4)));
typedef unsigned int u32x4 __attribute__((ext_vector_type(4)));

typedef __attribute__((address_space(3))) char        lds_char_t;
typedef const __attribute__((address_space(1))) char  gbl_char_t;

#define GLL16(gsrc, ldst) \
  __builtin_amdgcn_global_load_lds((gbl_char_t*)(gsrc), (lds_char_t*)(ldst), 16, 0, 0)

#define CONV1_T 26.3424f
#define KDIM 784
#define F1   500

// ------------------------------------------------------------------
// k_t0 (R12-measured): t0nib[b][p] (4-bit) = 15 - sum_t inp[b,t,p];
// pad pixels p>=784 -> 0xF. 400 B per batch row.
// ------------------------------------------------------------------
__global__ __launch_bounds__(256)
void k_t0(const float* __restrict__ inp, unsigned int* __restrict__ t0nib)
{
    const int gid = blockIdx.x * 256 + threadIdx.x;   // < 409600
    const int b   = gid / 100;
    const int p8  = gid % 100;
    if (p8 >= 98) { t0nib[gid] = 0xFFFFFFFFu; return; }

    const float* base = inp + (size_t)b * 11760 + p8 * 8;
    float cnt[8];
    #pragma unroll
    for (int e = 0; e < 8; ++e) cnt[e] = 0.f;
    #pragma unroll
    for (int t = 0; t < 15; ++t) {
        const f32x4 v0 = *(const f32x4*)(base + t * 784);
        const f32x4 v1 = *(const f32x4*)(base + t * 784 + 4);
        #pragma unroll
        for (int e = 0; e < 4; ++e) { cnt[e] += v0[e]; cnt[e + 4] += v1[e]; }
    }
    unsigned int d = 0;
    #pragma unroll
    for (int e = 0; e < 8; ++e) {
        const unsigned int t0 = 15u - (unsigned int)cnt[e];   // 0..14
        d |= (t0 & 15u) << (4 * e);
    }
    t0nib[gid] = d;
}

__global__ __launch_bounds__(256)
void k_zero(float* __restrict__ p, int n)
{
    const int i = blockIdx.x * 256 + threadIdx.x;
    if (i < n) p[i] = 0.f;
}

// rebuild 8 spike halfs from a t0 nibble dword: v[e] = (nib_e <= t)
__device__ __forceinline__
f16x8 rebuild_a(unsigned int d, int t)
{
    u32x4 br;
    #pragma unroll
    for (int h = 0; h < 4; ++h) {
        const unsigned int n0 = (d >> (8 * h))     & 15u;
        const unsigned int n1 = (d >> (8 * h + 4)) & 15u;
        br[h] = (n0 <= (unsigned)t ? 0x3C00u     : 0u)
              | (n1 <= (unsigned)t ? 0x3C000000u : 0u);
    }
    return __builtin_bit_cast(f16x8, br);
}

// ------------------------------------------------------------------
// k_prep (R3/R11/R12): split w1 [500x784] fp32 into f16 hi/lo, laid out
// exactly as the conv1 LDS tile bytes (GLL16-linear). Tile (nb*25+ks) is
// 32768 B: byte b -> part=b>>14 (0=hi,1=lo), nl=(b&16383)>>6,
// slot=(b>>4)&3, e=(b>>1)&7, k-chunk j = slot^((nl>>1)&3).
// ------------------------------------------------------------------
__global__ __launch_bounds__(256)
void k_prep(const float* __restrict__ w1, float* __restrict__ scratch)
{
    const int c = blockIdx.x * 256 + threadIdx.x;   // one 16B chunk each
    const int tile  = c >> 11;
    const int chunk = c & 2047;
    const int nb   = tile / 25;
    const int ks   = tile % 25;
    const int part = chunk >> 10;
    const int nl   = (chunk & 1023) >> 2;
    const int slot = chunk & 3;
    const int j    = slot ^ ((nl >> 1) & 3);
    const int k0   = ks * 32 + j * 8;
    const int ng   = nb * 256 + nl;

    f16x8 v;
    #pragma unroll
    for (int e = 0; e < 8; ++e) {
        const int kk = k0 + e;
        const float val = (ng < F1 && kk < KDIM) ? w1[ng * KDIM + kk] : 0.f;
        const _Float16 h = (_Float16)val;
        v[e] = part ? (_Float16)(val - (float)h) : h;
    }
    *(f16x8*)((char*)scratch + (size_t)c * 16) = v;
}

// ------------------------------------------------------------------
// k_conv1_t0 (R12 main loop verbatim) + fused conv3 epilogue.
// Tile BM=128, BN=256 (nb half), BK=32. 512 threads = 8 waves (2M x 4N).
// LDS: sA halfs @ [0,16384)B, sB halfs @ [16384,81920)B; the spike tile
// (64KB, swizzled) overlays [0,65536) after the main loop.
// ------------------------------------------------------------------
__global__ __launch_bounds__(512, 4)
void k_conv1_t0(const unsigned char* __restrict__ t0nib,
                const float* __restrict__ bsplit,
                const float* __restrict__ w3,
                float* __restrict__ spk1, float* __restrict__ thr1,
                float* __restrict__ pot3)
{
    __shared__ char smem[81920];
    _Float16* sAh = (_Float16*)smem;              // 2 x 4096 halfs
    _Float16* sBh = (_Float16*)(smem + 16384);    // 2 x 16384 halfs

    const int tid  = threadIdx.x;
    const int lane = tid & 63;
    const int wid  = tid >> 6;     // 0..7
    const int wm   = wid >> 2;     // 0..1 (M)
    const int wn   = wid & 3;      // 0..3 (N)
    const int lr   = lane & 15;
    const int kg   = lane >> 4;

    // XCD pairing: bx and bx^8 share the same A tile on the same XCD.
    const int bx   = blockIdx.x;                    // 0..959
    const int nb   = (bx >> 3) & 1;
    const int mblk = ((bx >> 4) << 3) | (bx & 7);   // 0..479
    const long long rowBase = (long long)mblk * 128;

    // A staging role: thread -> (row sm, 8-wide k-chunk sk8)
    const int sm  = tid >> 2;      // 0..127
    const int sk8 = tid & 3;
    const int aWr = sm * 32 + (sk8 ^ ((sm >> 1) & 3)) * 8;
    const long long am = rowBase + sm;
    const int at = (int)(am % 15);
    const unsigned char* atp = t0nib + (am / 15) * 400 + sk8 * 4;  // + ks*16

    // B: global_load_lds source (lane's 16B baked in); 4 x 1KB per wave
    const char* gBsrc = (const char*)bsplit + (size_t)(nb * 25) * 32768
                      + (size_t)wid * 4096 + (size_t)lane * 16;

    f32x4 acc[4][4];
    #pragma unroll
    for (int i = 0; i < 4; ++i)
        #pragma unroll
        for (int j = 0; j < 4; ++j) acc[i][j] = {0.f, 0.f, 0.f, 0.f};

    int aOff[4], bOff[4];
    #pragma unroll
    for (int fm = 0; fm < 4; ++fm) {
        const int r = wm * 64 + fm * 16 + lr;
        aOff[fm] = r * 32 + (kg ^ ((r >> 1) & 3)) * 8;
    }
    #pragma unroll
    for (int fn = 0; fn < 4; ++fn) {
        const int n = wn * 64 + fn * 16 + lr;
        bOff[fn] = n * 32 + (kg ^ ((n >> 1) & 3)) * 8;
    }

    // ---- prologue: stage ks=0 into buffer 0
    {
        #pragma unroll
        for (int i = 0; i < 4; ++i)
            GLL16(gBsrc + i * 1024,
                  (lds_char_t*)smem + 16384 + (size_t)wid * 4096 + i * 1024);
        const unsigned int d = *(const unsigned int*)(atp);
        *(f16x8*)&sAh[aWr] = rebuild_a(d, at);
    }
    __syncthreads();

    for (int ks = 0; ks < 25; ++ks) {
        const int  cur = ks & 1;
        const bool pf  = (ks + 1 < 25);

        // ---- issue prefetch for tile ks+1 into buffer cur^1
        unsigned int dNext = 0;
        if (pf) {
            dNext = *(const unsigned int*)(atp + (ks + 1) * 16);
            const char*  src = gBsrc + (size_t)(ks + 1) * 32768;
            lds_char_t*  dst = (lds_char_t*)smem + 16384 + (size_t)(cur ^ 1) * 32768
                             + (size_t)wid * 4096;
            #pragma unroll
            for (int i = 0; i < 4; ++i)
                GLL16(src + i * 1024, dst + i * 1024);
        }

        // ---- compute tile ks from buffer cur
        const _Float16* sAc = sAh + (size_t)cur * 4096;
        const _Float16* sBc = sBh + (size_t)cur * 16384;
        const f16x8 a0 = *(const f16x8*)&sAc[aOff[0]];
        const f16x8 a1 = *(const f16x8*)&sAc[aOff[1]];
        const f16x8 a2 = *(const f16x8*)&sAc[aOff[2]];
        const f16x8 a3 = *(const f16x8*)&sAc[aOff[3]];
        #pragma unroll
        for (int fn = 0; fn < 4; ++fn) {
            const f16x8 bh = *(const f16x8*)&sBc[bOff[fn]];
            const f16x8 bl = *(const f16x8*)&sBc[8192 + bOff[fn]];
            acc[0][fn] = __builtin_amdgcn_mfma_f32_16x16x32_f16(a0, bh, acc[0][fn], 0, 0, 0);
            acc[0][fn] = __builtin_amdgcn_mfma_f32_16x16x32_f16(a0, bl, acc[0][fn], 0, 0, 0);
            acc[1][fn] = __builtin_amdgcn_mfma_f32_16x16x32_f16(a1, bh, acc[1][fn], 0, 0, 0);
            acc[1][fn] = __builtin_amdgcn_mfma_f32_16x16x32_f16(a1, bl, acc[1][fn], 0, 0, 0);
            acc[2][fn] = __builtin_amdgcn_mfma_f32_16x16x32_f16(a2, bh, acc[2][fn], 0, 0, 0);
            acc[2][fn] = __builtin_amdgcn_mfma_f32_16x16x32_f16(a2, bl, acc[2][fn], 0, 0, 0);
            acc[3][fn] = __builtin_amdgcn_mfma_f32_16x16x32_f16(a3, bh, acc[3][fn], 0, 0, 0);
            acc[3][fn] = __builtin_amdgcn_mfma_f32_16x16x32_f16(a3, bl, acc[3][fn], 0, 0, 0);
        }

        // ---- finish A prefetch: rebuild + LDS write into buffer cur^1
        if (pf)
            *(f16x8*)&sAh[(size_t)(cur ^ 1) * 4096 + aWr] = rebuild_a(dNext, at);
        __syncthreads();
    }

    // ---- epilogue part 1: fire, global stores, spike tile -> swizzled LDS.
    // C/D layout: col = lane&15, row = (lane>>4)*4 + r.
    // Spike LDS: [128][256] f16, byte = rowL*512 + colL*2, ^= (rowL&7)<<4.
    #pragma unroll
    for (int fm = 0; fm < 4; ++fm) {
        #pragma unroll
        for (int fn = 0; fn < 4; ++fn) {
            const int colL = wn * 64 + fn * 16 + lr;
            const int ng   = nb * 256 + colL;
            #pragma unroll
            for (int r = 0; r < 4; ++r) {
                const int rowL = wm * 64 + fm * 16 + kg * 4 + r;
                const long long m = rowBase + rowL;
                const float p   = acc[fm][fn][r];
                const bool fire = (p >= CONV1_T);
                int sbyte = rowL * 512 + colL * 2;
                sbyte ^= ((rowL & 7) << 4);
                *(_Float16*)(smem + sbyte) = fire ? (_Float16)1.f : (_Float16)0.f;
                if (ng < F1) {
                    thr1[m * F1 + ng] = fire ? p : 0.f;
                    spk1[m * F1 + ng] = fire ? 1.f : 0.f;
                }
            }
        }
    }
    __syncthreads();

    // ---- epilogue part 2: conv3 partial = spikes[128x256] x w3^T[256x10].
    // Wave wid owns m-tile wid (16 rows). 8 MFMA over the 256-f slice.
    {
        f32x4 acc3 = {0.f, 0.f, 0.f, 0.f};
        const int mrow = wid * 16 + lr;
        #pragma unroll
        for (int kc = 0; kc < 8; ++kc) {
            int abyte = mrow * 512 + (kc * 32 + kg * 8) * 2;
            abyte ^= ((mrow & 7) << 4);
            const f16x8 a3 = *(const f16x8*)(smem + abyte);
            f16x8 b3;
            const int f0 = nb * 256 + kc * 32 + kg * 8;
            if (lr < 10) {
                const float* wr = w3 + lr * F1 + f0;
                #pragma unroll
                for (int e = 0; e < 8; ++e)
                    b3[e] = (f0 + e < F1) ? (_Float16)wr[e] : (_Float16)0.f;
            } else {
                #pragma unroll
                for (int e = 0; e < 8; ++e) b3[e] = (_Float16)0.f;
            }
            acc3 = __builtin_amdgcn_mfma_f32_16x16x32_f16(a3, b3, acc3, 0, 0, 0);
        }
        if (lr < 10) {
            #pragma unroll
            for (int r = 0; r < 4; ++r) {
                const long long m = rowBase + wid * 16 + kg * 4 + r;
                atomicAdd(&pot3[m * 10 + lr], acc3[r]);
            }
        }
    }
}

// ------------------------------------------------------------------
// k_conv1_f32 (R11 verbatim; fallback when d_ws too small).
// ------------------------------------------------------------------
__global__ __launch_bounds__(512, 4)
void k_conv1_f32(const float* __restrict__ inp, const float* __restrict__ bsplit,
                 float* __restrict__ spk1, float* __restrict__ thr1)
{
    __shared__ _Float16 sA[2][128 * 32];
    __shared__ _Float16 sB[2][2 * 256 * 32];

    const int tid  = threadIdx.x;
    const int lane = tid & 63;
    const int wid  = tid >> 6;
    const int wm   = wid >> 2;
    const int wn   = wid & 3;
    const int lr   = lane & 15;
    const int kg   = lane >> 4;

    const int bx   = blockIdx.x;
    const int nb   = (bx >> 3) & 1;
    const int mblk = ((bx >> 4) << 3) | (bx & 7);
    const long long rowBase = (long long)mblk * 128;

    const int sm  = tid >> 2;
    const int sk8 = tid & 3;
    const int aWr = sm * 32 + (sk8 ^ ((sm >> 1) & 3)) * 8;
    const float* gA = inp + (rowBase + sm) * KDIM + sk8 * 8;

    const char* gBsrc = (const char*)bsplit + (size_t)(nb * 25) * 32768
                      + (size_t)wid * 4096 + (size_t)lane * 16;

    f32x4 acc[4][4];
    #pragma unroll
    for (int i = 0; i < 4; ++i)
        #pragma unroll
        for (int j = 0; j < 4; ++j) acc[i][j] = {0.f, 0.f, 0.f, 0.f};

    int aOff[4], bOff[4];
    #pragma unroll
    for (int fm = 0; fm < 4; ++fm) {
        const int r = wm * 64 + fm * 16 + lr;
        aOff[fm] = r * 32 + (kg ^ ((r >> 1) & 3)) * 8;
    }
    #pragma unroll
    for (int fn = 0; fn < 4; ++fn) {
        const int n = wn * 64 + fn * 16 + lr;
        bOff[fn] = n * 32 + (kg ^ ((n >> 1) & 3)) * 8;
    }

    {
        const f32x4 x0 = *(const f32x4*)(gA);
        const f32x4 x1 = *(const f32x4*)(gA + 4);
        #pragma unroll
        for (int i = 0; i < 4; ++i)
            GLL16(gBsrc + i * 1024, (lds_char_t*)&sB[0][0] + wid * 4096 + i * 1024);
        f16x8 v;
        #pragma unroll
        for (int e = 0; e < 4; ++e) { v[e] = (_Float16)x0[e]; v[e + 4] = (_Float16)x1[e]; }
        *(f16x8*)&sA[0][aWr] = v;
    }
    __syncthreads();

    for (int ks = 0; ks < 25; ++ks) {
        const int  cur = ks & 1;
        const bool pf  = (ks + 1 < 25);

        f32x4 x0 = {0.f, 0.f, 0.f, 0.f}, x1 = {0.f, 0.f, 0.f, 0.f};
        bool av = false;
        if (pf) {
            const int k0 = (ks + 1) * 32 + sk8 * 8;
            av = (k0 + 8 <= KDIM);
            if (av) {
                x0 = *(const f32x4*)(gA + (ks + 1) * 32);
                x1 = *(const f32x4*)(gA + (ks + 1) * 32 + 4);
            }
            const char*  src = gBsrc + (size_t)(ks + 1) * 32768;
            lds_char_t*  dst = (lds_char_t*)&sB[cur ^ 1][0] + wid * 4096;
            #pragma unroll
            for (int i = 0; i < 4; ++i)
                GLL16(src + i * 1024, dst + i * 1024);
        }

        const f16x8 a0 = *(const f16x8*)&sA[cur][aOff[0]];
        const f16x8 a1 = *(const f16x8*)&sA[cur][aOff[1]];
        const f16x8 a2 = *(const f16x8*)&sA[cur][aOff[2]];
        const f16x8 a3 = *(const f16x8*)&sA[cur][aOff[3]];
        #pragma unroll
        for (int fn = 0; fn < 4; ++fn) {
            const f16x8 bh = *(const f16x8*)&sB[cur][bOff[fn]];
            const f16x8 bl = *(const f16x8*)&sB[cur][8192 + bOff[fn]];
            acc[0][fn] = __builtin_amdgcn_mfma_f32_16x16x32_f16(a0, bh, acc[0][fn], 0, 0, 0);
            acc[0][fn] = __builtin_amdgcn_mfma_f32_16x16x32_f16(a0, bl, acc[0][fn], 0, 0, 0);
            acc[1][fn] = __builtin_amdgcn_mfma_f32_16x16x32_f16(a1, bh, acc[1][fn], 0, 0, 0);
            acc[1][fn] = __builtin_amdgcn_mfma_f32_16x16x32_f16(a1, bl, acc[1][fn], 0, 0, 0);
            acc[2][fn] = __builtin_amdgcn_mfma_f32_16x16x32_f16(a2, bh, acc[2][fn], 0, 0, 0);
            acc[2][fn] = __builtin_amdgcn_mfma_f32_16x16x32_f16(a2, bl, acc[2][fn], 0, 0, 0);
            acc[3][fn] = __builtin_amdgcn_mfma_f32_16x16x32_f16(a3, bh, acc[3][fn], 0, 0, 0);
            acc[3][fn] = __builtin_amdgcn_mfma_f32_16x16x32_f16(a3, bl, acc[3][fn], 0, 0, 0);
        }

        if (pf) {
            f16x8 v;
            #pragma unroll
            for (int e = 0; e < 4; ++e) {
                v[e]     = av ? (_Float16)x0[e] : (_Float16)0.f;
                v[e + 4] = av ? (_Float16)x1[e] : (_Float16)0.f;
            }
            *(f16x8*)&sA[cur ^ 1][aWr] = v;
        }
        __syncthreads();
    }

    #pragma unroll
    for (int fm = 0; fm < 4; ++fm) {
        #pragma unroll
        for (int fn = 0; fn < 4; ++fn) {
            const int ng = nb * 256 + wn * 64 + fn * 16 + lr;
            if (ng < F1) {
                #pragma unroll
                for (int r = 0; r < 4; ++r) {
                    const long long m = rowBase + wm * 64 + fm * 16 + kg * 4 + r;
                    const float p   = acc[fm][fn][r];
                    const bool fire = (p >= CONV1_T);
                    thr1[m * F1 + ng] = fire ? p : 0.f;
                    spk1[m * F1 + ng] = fire ? 1.f : 0.f;
                }
            }
        }
    }
}

// ------------------------------------------------------------------
// k_conv3 (R5-verified; fallback path only): pot3 via 16x16x32 f16 MFMA.
// ------------------------------------------------------------------
__global__ __launch_bounds__(256)
void k_conv3(const float* __restrict__ spk1, const float* __restrict__ w3,
             float* __restrict__ pot3)
{
    const int tid  = threadIdx.x;
    const int lane = tid & 63;
    const int wid  = tid >> 6;
    const int gw   = blockIdx.x * 4 + wid;    // 0..3839
    const long long row0 = (long long)gw * 16;
    const int lr = lane & 15;
    const int kg = lane >> 4;
    const int n  = (lr < 10) ? lr : 0;

    const float* arow = spk1 + (row0 + lr) * F1;
    const float* brow = w3 + (size_t)n * F1;

    f32x4 acc = {0.f, 0.f, 0.f, 0.f};
    #pragma unroll
    for (int ks = 0; ks < 16; ++ks) {
        const int k0 = ks * 32 + kg * 8;
        f16x8 a, b;
        if (k0 + 8 <= F1) {
            const f32x4 a0 = *(const f32x4*)(arow + k0);
            const f32x4 a1 = *(const f32x4*)(arow + k0 + 4);
            const f32x4 b0 = *(const f32x4*)(brow + k0);
            const f32x4 b1 = *(const f32x4*)(brow + k0 + 4);
            #pragma unroll
            for (int e = 0; e < 4; ++e) {
                a[e] = (_Float16)a0[e]; a[e + 4] = (_Float16)a1[e];
                b[e] = (_Float16)b0[e]; b[e + 4] = (_Float16)b1[e];
            }
        } else {
            #pragma unroll
            for (int e = 0; e < 8; ++e) {
                const int k = k0 + e;
                a[e] = (k < F1) ? (_Float16)arow[k] : (_Float16)0.f;
                b[e] = (k < F1) ? (_Float16)brow[k] : (_Float16)0.f;
            }
        }
        acc = __builtin_amdgcn_mfma_f32_16x16x32_f16(a, b, acc, 0, 0, 0);
    }
    if (lr < 10) {
        #pragma unroll
        for (int r = 0; r < 4; ++r) {
            const long long m = row0 + kg * 4 + r;
            pot3[m * 10 + lr] = acc[r];
        }
    }
}

// ------------------------------------------------------------------
// k_winner: winner-take-all per batch, faithful to reference algebra.
// ------------------------------------------------------------------
__global__ __launch_bounds__(256)
void k_winner(const float* __restrict__ pot3, float* __restrict__ outCls, int nB)
{
    const int b = blockIdx.x * 256 + threadIdx.x;
    if (b >= nB) return;
    const float* p = pot3 + (long long)b * 150 + 140;   // t = 14 row

    float pv[10], s[10];
    float mv = 0.f;
    #pragma unroll
    for (int g = 0; g < 10; ++g) {
        const float v = p[g];
        pv[g] = v;
        s[g]  = (v > 0.f) ? 1.f : ((v < 0.f) ? -1.f : 0.f);
        mv = fmaxf(mv, s[g] * v);
    }
    const float vbig = mv * 15.f;
    float bm = -INFINITY; int bi = 0;
    #pragma unroll
    for (int g = 0; g < 10; ++g) {
        const float tot = s[g] * pv[g] + s[g] * vbig;
        if (tot > bm) { bm = tot; bi = g; }
    }
    outCls[b] = (bm != 0.f) ? (float)bi : -1.f;
}

// ------------------------------------------------------------------
extern "C" void kernel_launch(void* const* d_in, const int* in_sizes, int n_in,
                              void* d_out, int out_size, void* d_ws, size_t ws_size,
                              hipStream_t stream)
{
    const float* inp = (const float*)d_in[0];
    const float* w1  = (const float*)d_in[1];
    const float* w3  = (const float*)d_in[2];

    float* out  = (float*)d_out;
    float* spk1 = out;
    float* thr1 = out + 30720000LL;
    float* pot3 = out + 61440000LL;
    float* cls  = out + 62054400LL;

    if (ws_size >= 3276800) {
        // fused path: w1split (1638400 B) + t0nib (1638400 B) in d_ws
        float*        w1split = (float*)d_ws;
        unsigned int* t0nib   = (unsigned int*)((char*)d_ws + 1638400);
        k_prep    <<<400,  256, 0, stream>>>(w1, w1split);
        k_t0      <<<1600, 256, 0, stream>>>(inp, t0nib);
        k_zero    <<<2400, 256, 0, stream>>>(pot3, 614400);
        k_conv1_t0<<<960,  512, 0, stream>>>((const unsigned char*)t0nib, w1split,
                                             w3, spk1, thr1, pot3);
    } else {
        // fallback: R11-exact (scratch borrows pot3; conv3 separate)
        float* scratch = pot3;
        k_prep     <<<400, 256, 0, stream>>>(w1, scratch);
        k_conv1_f32<<<960, 512, 0, stream>>>(inp, scratch, spk1, thr1);
        k_conv3    <<<960, 256, 0, stream>>>(spk1, w3, pot3);
    }
    k_winner<<<16, 256, 0, stream>>>(pot3, cls, 4096);
}

// Round 16
// 177.202 us; speedup vs baseline: 1.7558x; 1.0589x over previous
//
#include <hip/hip_runtime.h>
#include <hip/hip_bf16.h>
#include <stdint.h>

// MozafariMNIST2018 forward. B=4096, T=15, HW=784, F1=500, F3=10.
// Output layout (float32, concatenated):
//   spk1 [4096*15*500] @ 0
//   thr1 [4096*15*500] @ 30720000
//   pot3 [4096*15*10]  @ 61440000
//   cls  [4096]        @ 62054400
//
// R16 = R15 (187.6us) with the separate k_t0 pass ELIMINATED: each conv1
// block computes its own <=10 batches' t0 nibbles in a prologue (k_t0's
// exact arithmetic -> identical bits; duplicate writers write identical
// values -> race-free), writes them to the global scratch, barriers, then
// runs the R15 main loop + fused conv3 epilogue byte-identically.

typedef _Float16     f16x8 __attribute__((ext_vector_type(8)));
typedef float        f32x4 __attribute__((ext_vector_type(4)));
typedef unsigned int u32x4 __attribute__((ext_vector_type(4)));

typedef __attribute__((address_space(3))) char        lds_char_t;
typedef const __attribute__((address_space(1))) char  gbl_char_t;

#define GLL16(gsrc, ldst) \
  __builtin_amdgcn_global_load_lds((gbl_char_t*)(gsrc), (lds_char_t*)(ldst), 16, 0, 0)

#define CONV1_T 26.3424f
#define KDIM 784
#define F1   500

__global__ __launch_bounds__(256)
void k_zero(float* __restrict__ p, int n)
{
    const int i = blockIdx.x * 256 + threadIdx.x;
    if (i < n) p[i] = 0.f;
}

// rebuild 8 spike halfs from a t0 nibble dword: v[e] = (nib_e <= t)
__device__ __forceinline__
f16x8 rebuild_a(unsigned int d, int t)
{
    u32x4 br;
    #pragma unroll
    for (int h = 0; h < 4; ++h) {
        const unsigned int n0 = (d >> (8 * h))     & 15u;
        const unsigned int n1 = (d >> (8 * h + 4)) & 15u;
        br[h] = (n0 <= (unsigned)t ? 0x3C00u     : 0u)
              | (n1 <= (unsigned)t ? 0x3C000000u : 0u);
    }
    return __builtin_bit_cast(f16x8, br);
}

// ------------------------------------------------------------------
// k_prep (R3/R11/R12): split w1 [500x784] fp32 into f16 hi/lo, laid out
// exactly as the conv1 LDS tile bytes (GLL16-linear). Tile (nb*25+ks) is
// 32768 B: byte b -> part=b>>14 (0=hi,1=lo), nl=(b&16383)>>6,
// slot=(b>>4)&3, e=(b>>1)&7, k-chunk j = slot^((nl>>1)&3).
// ------------------------------------------------------------------
__global__ __launch_bounds__(256)
void k_prep(const float* __restrict__ w1, float* __restrict__ scratch)
{
    const int c = blockIdx.x * 256 + threadIdx.x;   // one 16B chunk each
    const int tile  = c >> 11;
    const int chunk = c & 2047;
    const int nb   = tile / 25;
    const int ks   = tile % 25;
    const int part = chunk >> 10;
    const int nl   = (chunk & 1023) >> 2;
    const int slot = chunk & 3;
    const int j    = slot ^ ((nl >> 1) & 3);
    const int k0   = ks * 32 + j * 8;
    const int ng   = nb * 256 + nl;

    f16x8 v;
    #pragma unroll
    for (int e = 0; e < 8; ++e) {
        const int kk = k0 + e;
        const float val = (ng < F1 && kk < KDIM) ? w1[ng * KDIM + kk] : 0.f;
        const _Float16 h = (_Float16)val;
        v[e] = part ? (_Float16)(val - (float)h) : h;
    }
    *(f16x8*)((char*)scratch + (size_t)c * 16) = v;
}

// ------------------------------------------------------------------
// k_conv1_t0: prologue computes this block's t0 nibbles (k_t0 arithmetic
// verbatim), then R15's main loop + fused conv3 epilogue, byte-identical.
// Tile BM=128, BN=256 (nb half), BK=32. 512 threads = 8 waves (2M x 4N).
// ------------------------------------------------------------------
__global__ __launch_bounds__(512, 4)
void k_conv1_t0(const float* __restrict__ inp,
                unsigned int* __restrict__ t0nib,
                const float* __restrict__ bsplit,
                const float* __restrict__ w3,
                float* __restrict__ spk1, float* __restrict__ thr1,
                float* __restrict__ pot3)
{
    __shared__ char smem[81920];
    _Float16* sAh = (_Float16*)smem;              // 2 x 4096 halfs
    _Float16* sBh = (_Float16*)(smem + 16384);    // 2 x 16384 halfs

    const int tid  = threadIdx.x;
    const int lane = tid & 63;
    const int wid  = tid >> 6;     // 0..7
    const int wm   = wid >> 2;     // 0..1 (M)
    const int wn   = wid & 3;      // 0..3 (N)
    const int lr   = lane & 15;
    const int kg   = lane >> 4;

    // XCD pairing: bx and bx^8 share the same A tile on the same XCD.
    const int bx   = blockIdx.x;                    // 0..959
    const int nb   = (bx >> 3) & 1;
    const int mblk = ((bx >> 4) << 3) | (bx & 7);   // 0..479
    const long long rowBase = (long long)mblk * 128;

    // ---- phase 0: compute this block's t0 rows (k_t0 arithmetic verbatim)
    {
        const int bStart = (int)(rowBase / 15);
        const int bEnd   = (int)((rowBase + 127) / 15);
        const int nWork  = (bEnd - bStart + 1) * 100;   // <= 1000
        for (int w = tid; w < nWork; w += 512) {
            const int b  = bStart + w / 100;
            const int p8 = w % 100;
            unsigned int d;
            if (p8 >= 98) {
                d = 0xFFFFFFFFu;
            } else {
                const float* base = inp + (size_t)b * 11760 + p8 * 8;
                float cnt[8];
                #pragma unroll
                for (int e = 0; e < 8; ++e) cnt[e] = 0.f;
                #pragma unroll
                for (int t = 0; t < 15; ++t) {
                    const f32x4 v0 = *(const f32x4*)(base + t * 784);
                    const f32x4 v1 = *(const f32x4*)(base + t * 784 + 4);
                    #pragma unroll
                    for (int e = 0; e < 4; ++e) { cnt[e] += v0[e]; cnt[e + 4] += v1[e]; }
                }
                d = 0;
                #pragma unroll
                for (int e = 0; e < 8; ++e) {
                    const unsigned int t0 = 15u - (unsigned int)cnt[e];   // 0..14
                    d |= (t0 & 15u) << (4 * e);
                }
            }
            t0nib[b * 100 + p8] = d;
        }
    }
    __syncthreads();

    // A staging role: thread -> (row sm, 8-wide k-chunk sk8)
    const int sm  = tid >> 2;      // 0..127
    const int sk8 = tid & 3;
    const int aWr = sm * 32 + (sk8 ^ ((sm >> 1) & 3)) * 8;
    const long long am = rowBase + sm;
    const int at = (int)(am % 15);
    const unsigned char* atp = (const unsigned char*)t0nib
                             + (am / 15) * 400 + sk8 * 4;          // + ks*16

    // B: global_load_lds source (lane's 16B baked in); 4 x 1KB per wave
    const char* gBsrc = (const char*)bsplit + (size_t)(nb * 25) * 32768
                      + (size_t)wid * 4096 + (size_t)lane * 16;

    f32x4 acc[4][4];
    #pragma unroll
    for (int i = 0; i < 4; ++i)
        #pragma unroll
        for (int j = 0; j < 4; ++j) acc[i][j] = {0.f, 0.f, 0.f, 0.f};

    int aOff[4], bOff[4];
    #pragma unroll
    for (int fm = 0; fm < 4; ++fm) {
        const int r = wm * 64 + fm * 16 + lr;
        aOff[fm] = r * 32 + (kg ^ ((r >> 1) & 3)) * 8;
    }
    #pragma unroll
    for (int fn = 0; fn < 4; ++fn) {
        const int n = wn * 64 + fn * 16 + lr;
        bOff[fn] = n * 32 + (kg ^ ((n >> 1) & 3)) * 8;
    }

    // ---- prologue: stage ks=0 into buffer 0
    {
        #pragma unroll
        for (int i = 0; i < 4; ++i)
            GLL16(gBsrc + i * 1024,
                  (lds_char_t*)smem + 16384 + (size_t)wid * 4096 + i * 1024);
        const unsigned int d = *(const unsigned int*)(atp);
        *(f16x8*)&sAh[aWr] = rebuild_a(d, at);
    }
    __syncthreads();

    for (int ks = 0; ks < 25; ++ks) {
        const int  cur = ks & 1;
        const bool pf  = (ks + 1 < 25);

        // ---- issue prefetch for tile ks+1 into buffer cur^1
        unsigned int dNext = 0;
        if (pf) {
            dNext = *(const unsigned int*)(atp + (ks + 1) * 16);
            const char*  src = gBsrc + (size_t)(ks + 1) * 32768;
            lds_char_t*  dst = (lds_char_t*)smem + 16384 + (size_t)(cur ^ 1) * 32768
                             + (size_t)wid * 4096;
            #pragma unroll
            for (int i = 0; i < 4; ++i)
                GLL16(src + i * 1024, dst + i * 1024);
        }

        // ---- compute tile ks from buffer cur
        const _Float16* sAc = sAh + (size_t)cur * 4096;
        const _Float16* sBc = sBh + (size_t)cur * 16384;
        const f16x8 a0 = *(const f16x8*)&sAc[aOff[0]];
        const f16x8 a1 = *(const f16x8*)&sAc[aOff[1]];
        const f16x8 a2 = *(const f16x8*)&sAc[aOff[2]];
        const f16x8 a3 = *(const f16x8*)&sAc[aOff[3]];
        #pragma unroll
        for (int fn = 0; fn < 4; ++fn) {
            const f16x8 bh = *(const f16x8*)&sBc[bOff[fn]];
            const f16x8 bl = *(const f16x8*)&sBc[8192 + bOff[fn]];
            acc[0][fn] = __builtin_amdgcn_mfma_f32_16x16x32_f16(a0, bh, acc[0][fn], 0, 0, 0);
            acc[0][fn] = __builtin_amdgcn_mfma_f32_16x16x32_f16(a0, bl, acc[0][fn], 0, 0, 0);
            acc[1][fn] = __builtin_amdgcn_mfma_f32_16x16x32_f16(a1, bh, acc[1][fn], 0, 0, 0);
            acc[1][fn] = __builtin_amdgcn_mfma_f32_16x16x32_f16(a1, bl, acc[1][fn], 0, 0, 0);
            acc[2][fn] = __builtin_amdgcn_mfma_f32_16x16x32_f16(a2, bh, acc[2][fn], 0, 0, 0);
            acc[2][fn] = __builtin_amdgcn_mfma_f32_16x16x32_f16(a2, bl, acc[2][fn], 0, 0, 0);
            acc[3][fn] = __builtin_amdgcn_mfma_f32_16x16x32_f16(a3, bh, acc[3][fn], 0, 0, 0);
            acc[3][fn] = __builtin_amdgcn_mfma_f32_16x16x32_f16(a3, bl, acc[3][fn], 0, 0, 0);
        }

        // ---- finish A prefetch: rebuild + LDS write into buffer cur^1
        if (pf)
            *(f16x8*)&sAh[(size_t)(cur ^ 1) * 4096 + aWr] = rebuild_a(dNext, at);
        __syncthreads();
    }

    // ---- epilogue part 1: fire, global stores, spike tile -> swizzled LDS.
    // C/D layout: col = lane&15, row = (lane>>4)*4 + r.
    // Spike LDS: [128][256] f16, byte = rowL*512 + colL*2, ^= (rowL&7)<<4.
    #pragma unroll
    for (int fm = 0; fm < 4; ++fm) {
        #pragma unroll
        for (int fn = 0; fn < 4; ++fn) {
            const int colL = wn * 64 + fn * 16 + lr;
            const int ng   = nb * 256 + colL;
            #pragma unroll
            for (int r = 0; r < 4; ++r) {
                const int rowL = wm * 64 + fm * 16 + kg * 4 + r;
                const long long m = rowBase + rowL;
                const float p   = acc[fm][fn][r];
                const bool fire = (p >= CONV1_T);
                int sbyte = rowL * 512 + colL * 2;
                sbyte ^= ((rowL & 7) << 4);
                *(_Float16*)(smem + sbyte) = fire ? (_Float16)1.f : (_Float16)0.f;
                if (ng < F1) {
                    thr1[m * F1 + ng] = fire ? p : 0.f;
                    spk1[m * F1 + ng] = fire ? 1.f : 0.f;
                }
            }
        }
    }
    __syncthreads();

    // ---- epilogue part 2: conv3 partial = spikes[128x256] x w3^T[256x10].
    {
        f32x4 acc3 = {0.f, 0.f, 0.f, 0.f};
        const int mrow = wid * 16 + lr;
        #pragma unroll
        for (int kc = 0; kc < 8; ++kc) {
            int abyte = mrow * 512 + (kc * 32 + kg * 8) * 2;
            abyte ^= ((mrow & 7) << 4);
            const f16x8 a3 = *(const f16x8*)(smem + abyte);
            f16x8 b3;
            const int f0 = nb * 256 + kc * 32 + kg * 8;
            if (lr < 10) {
                const float* wr = w3 + lr * F1 + f0;
                #pragma unroll
                for (int e = 0; e < 8; ++e)
                    b3[e] = (f0 + e < F1) ? (_Float16)wr[e] : (_Float16)0.f;
            } else {
                #pragma unroll
                for (int e = 0; e < 8; ++e) b3[e] = (_Float16)0.f;
            }
            acc3 = __builtin_amdgcn_mfma_f32_16x16x32_f16(a3, b3, acc3, 0, 0, 0);
        }
        if (lr < 10) {
            #pragma unroll
            for (int r = 0; r < 4; ++r) {
                const long long m = rowBase + wid * 16 + kg * 4 + r;
                atomicAdd(&pot3[m * 10 + lr], acc3[r]);
            }
        }
    }
}

// ------------------------------------------------------------------
// k_conv1_f32 (R11 verbatim; fallback when d_ws too small).
// ------------------------------------------------------------------
__global__ __launch_bounds__(512, 4)
void k_conv1_f32(const float* __restrict__ inp, const float* __restrict__ bsplit,
                 float* __restrict__ spk1, float* __restrict__ thr1)
{
    __shared__ _Float16 sA[2][128 * 32];
    __shared__ _Float16 sB[2][2 * 256 * 32];

    const int tid  = threadIdx.x;
    const int lane = tid & 63;
    const int wid  = tid >> 6;
    const int wm   = wid >> 2;
    const int wn   = wid & 3;
    const int lr   = lane & 15;
    const int kg   = lane >> 4;

    const int bx   = blockIdx.x;
    const int nb   = (bx >> 3) & 1;
    const int mblk = ((bx >> 4) << 3) | (bx & 7);
    const long long rowBase = (long long)mblk * 128;

    const int sm  = tid >> 2;
    const int sk8 = tid & 3;
    const int aWr = sm * 32 + (sk8 ^ ((sm >> 1) & 3)) * 8;
    const float* gA = inp + (rowBase + sm) * KDIM + sk8 * 8;

    const char* gBsrc = (const char*)bsplit + (size_t)(nb * 25) * 32768
                      + (size_t)wid * 4096 + (size_t)lane * 16;

    f32x4 acc[4][4];
    #pragma unroll
    for (int i = 0; i < 4; ++i)
        #pragma unroll
        for (int j = 0; j < 4; ++j) acc[i][j] = {0.f, 0.f, 0.f, 0.f};

    int aOff[4], bOff[4];
    #pragma unroll
    for (int fm = 0; fm < 4; ++fm) {
        const int r = wm * 64 + fm * 16 + lr;
        aOff[fm] = r * 32 + (kg ^ ((r >> 1) & 3)) * 8;
    }
    #pragma unroll
    for (int fn = 0; fn < 4; ++fn) {
        const int n = wn * 64 + fn * 16 + lr;
        bOff[fn] = n * 32 + (kg ^ ((n >> 1) & 3)) * 8;
    }

    {
        const f32x4 x0 = *(const f32x4*)(gA);
        const f32x4 x1 = *(const f32x4*)(gA + 4);
        #pragma unroll
        for (int i = 0; i < 4; ++i)
            GLL16(gBsrc + i * 1024, (lds_char_t*)&sB[0][0] + wid * 4096 + i * 1024);
        f16x8 v;
        #pragma unroll
        for (int e = 0; e < 4; ++e) { v[e] = (_Float16)x0[e]; v[e + 4] = (_Float16)x1[e]; }
        *(f16x8*)&sA[0][aWr] = v;
    }
    __syncthreads();

    for (int ks = 0; ks < 25; ++ks) {
        const int  cur = ks & 1;
        const bool pf  = (ks + 1 < 25);

        f32x4 x0 = {0.f, 0.f, 0.f, 0.f}, x1 = {0.f, 0.f, 0.f, 0.f};
        bool av = false;
        if (pf) {
            const int k0 = (ks + 1) * 32 + sk8 * 8;
            av = (k0 + 8 <= KDIM);
            if (av) {
                x0 = *(const f32x4*)(gA + (ks + 1) * 32);
                x1 = *(const f32x4*)(gA + (ks + 1) * 32 + 4);
            }
            const char*  src = gBsrc + (size_t)(ks + 1) * 32768;
            lds_char_t*  dst = (lds_char_t*)&sB[cur ^ 1][0] + wid * 4096;
            #pragma unroll
            for (int i = 0; i < 4; ++i)
                GLL16(src + i * 1024, dst + i * 1024);
        }

        const f16x8 a0 = *(const f16x8*)&sA[cur][aOff[0]];
        const f16x8 a1 = *(const f16x8*)&sA[cur][aOff[1]];
        const f16x8 a2 = *(const f16x8*)&sA[cur][aOff[2]];
        const f16x8 a3 = *(const f16x8*)&sA[cur][aOff[3]];
        #pragma unroll
        for (int fn = 0; fn < 4; ++fn) {
            const f16x8 bh = *(const f16x8*)&sB[cur][bOff[fn]];
            const f16x8 bl = *(const f16x8*)&sB[cur][8192 + bOff[fn]];
            acc[0][fn] = __builtin_amdgcn_mfma_f32_16x16x32_f16(a0, bh, acc[0][fn], 0, 0, 0);
            acc[0][fn] = __builtin_amdgcn_mfma_f32_16x16x32_f16(a0, bl, acc[0][fn], 0, 0, 0);
            acc[1][fn] = __builtin_amdgcn_mfma_f32_16x16x32_f16(a1, bh, acc[1][fn], 0, 0, 0);
            acc[1][fn] = __builtin_amdgcn_mfma_f32_16x16x32_f16(a1, bl, acc[1][fn], 0, 0, 0);
            acc[2][fn] = __builtin_amdgcn_mfma_f32_16x16x32_f16(a2, bh, acc[2][fn], 0, 0, 0);
            acc[2][fn] = __builtin_amdgcn_mfma_f32_16x16x32_f16(a2, bl, acc[2][fn], 0, 0, 0);
            acc[3][fn] = __builtin_amdgcn_mfma_f32_16x16x32_f16(a3, bh, acc[3][fn], 0, 0, 0);
            acc[3][fn] = __builtin_amdgcn_mfma_f32_16x16x32_f16(a3, bl, acc[3][fn], 0, 0, 0);
        }

        if (pf) {
            f16x8 v;
            #pragma unroll
            for (int e = 0; e < 4; ++e) {
                v[e]     = av ? (_Float16)x0[e] : (_Float16)0.f;
                v[e + 4] = av ? (_Float16)x1[e] : (_Float16)0.f;
            }
            *(f16x8*)&sA[cur ^ 1][aWr] = v;
        }
        __syncthreads();
    }

    #pragma unroll
    for (int fm = 0; fm < 4; ++fm) {
        #pragma unroll
        for (int fn = 0; fn < 4; ++fn) {
            const int ng = nb * 256 + wn * 64 + fn * 16 + lr;
            if (ng < F1) {
                #pragma unroll
                for (int r = 0; r < 4; ++r) {
                    const long long m = rowBase + wm * 64 + fm * 16 + kg * 4 + r;
                    const float p   = acc[fm][fn][r];
                    const bool fire = (p >= CONV1_T);
                    thr1[m * F1 + ng] = fire ? p : 0.f;
                    spk1[m * F1 + ng] = fire ? 1.f : 0.f;
                }
            }
        }
    }
}

// ------------------------------------------------------------------
// k_conv3 (R5-verified; fallback path only): pot3 via 16x16x32 f16 MFMA.
// ------------------------------------------------------------------
__global__ __launch_bounds__(256)
void k_conv3(const float* __restrict__ spk1, const float* __restrict__ w3,
             float* __restrict__ pot3)
{
    const int tid  = threadIdx.x;
    const int lane = tid & 63;
    const int wid  = tid >> 6;
    const int gw   = blockIdx.x * 4 + wid;    // 0..3839
    const long long row0 = (long long)gw * 16;
    const int lr = lane & 15;
    const int kg = lane >> 4;
    const int n  = (lr < 10) ? lr : 0;

    const float* arow = spk1 + (row0 + lr) * F1;
    const float* brow = w3 + (size_t)n * F1;

    f32x4 acc = {0.f, 0.f, 0.f, 0.f};
    #pragma unroll
    for (int ks = 0; ks < 16; ++ks) {
        const int k0 = ks * 32 + kg * 8;
        f16x8 a, b;
        if (k0 + 8 <= F1) {
            const f32x4 a0 = *(const f32x4*)(arow + k0);
            const f32x4 a1 = *(const f32x4*)(arow + k0 + 4);
            const f32x4 b0 = *(const f32x4*)(brow + k0);
            const f32x4 b1 = *(const f32x4*)(brow + k0 + 4);
            #pragma unroll
            for (int e = 0; e < 4; ++e) {
                a[e] = (_Float16)a0[e]; a[e + 4] = (_Float16)a1[e];
                b[e] = (_Float16)b0[e]; b[e + 4] = (_Float16)b1[e];
            }
        } else {
            #pragma unroll
            for (int e = 0; e < 8; ++e) {
                const int k = k0 + e;
                a[e] = (k < F1) ? (_Float16)arow[k] : (_Float16)0.f;
                b[e] = (k < F1) ? (_Float16)brow[k] : (_Float16)0.f;
            }
        }
        acc = __builtin_amdgcn_mfma_f32_16x16x32_f16(a, b, acc, 0, 0, 0);
    }
    if (lr < 10) {
        #pragma unroll
        for (int r = 0; r < 4; ++r) {
            const long long m = row0 + kg * 4 + r;
            pot3[m * 10 + lr] = acc[r];
        }
    }
}

// ------------------------------------------------------------------
// k_winner: winner-take-all per batch, faithful to reference algebra.
// ------------------------------------------------------------------
__global__ __launch_bounds__(256)
void k_winner(const float* __restrict__ pot3, float* __restrict__ outCls, int nB)
{
    const int b = blockIdx.x * 256 + threadIdx.x;
    if (b >= nB) return;
    const float* p = pot3 + (long long)b * 150 + 140;   // t = 14 row

    float pv[10], s[10];
    float mv = 0.f;
    #pragma unroll
    for (int g = 0; g < 10; ++g) {
        const float v = p[g];
        pv[g] = v;
        s[g]  = (v > 0.f) ? 1.f : ((v < 0.f) ? -1.f : 0.f);
        mv = fmaxf(mv, s[g] * v);
    }
    const float vbig = mv * 15.f;
    float bm = -INFINITY; int bi = 0;
    #pragma unroll
    for (int g = 0; g < 10; ++g) {
        const float tot = s[g] * pv[g] + s[g] * vbig;
        if (tot > bm) { bm = tot; bi = g; }
    }
    outCls[b] = (bm != 0.f) ? (float)bi : -1.f;
}

// ------------------------------------------------------------------
extern "C" void kernel_launch(void* const* d_in, const int* in_sizes, int n_in,
                              void* d_out, int out_size, void* d_ws, size_t ws_size,
                              hipStream_t stream)
{
    const float* inp = (const float*)d_in[0];
    const float* w1  = (const float*)d_in[1];
    const float* w3  = (const float*)d_in[2];

    float* out  = (float*)d_out;
    float* spk1 = out;
    float* thr1 = out + 30720000LL;
    float* pot3 = out + 61440000LL;
    float* cls  = out + 62054400LL;

    if (ws_size >= 3276800) {
        // fused path: w1split (1638400 B) + t0nib (1638400 B) in d_ws;
        // t0nib is computed by conv1's own prologue (no separate pass).
        float*        w1split = (float*)d_ws;
        unsigned int* t0nib   = (unsigned int*)((char*)d_ws + 1638400);
        k_prep    <<<400,  256, 0, stream>>>(w1, w1split);
        k_zero    <<<2400, 256, 0, stream>>>(pot3, 614400);
        k_conv1_t0<<<960,  512, 0, stream>>>(inp, t0nib, w1split, w3,
                                             spk1, thr1, pot3);
    } else {
        // fallback: R11-exact (scratch borrows pot3; conv3 separate)
        float* scratch = pot3;
        k_prep     <<<400, 256, 0, stream>>>(w1, scratch);
        k_conv1_f32<<<960, 512, 0, stream>>>(inp, scratch, spk1, thr1);
        k_conv3    <<<960, 256, 0, stream>>>(spk1, w3, pot3);
    }
    k_winner<<<16, 256, 0, stream>>>(pot3, cls, 4096);
}

// Round 17
// 175.105 us; speedup vs baseline: 1.7768x; 1.0120x over previous
//
#include <hip/hip_runtime.h>
#include <hip/hip_bf16.h>
#include <stdint.h>

// MozafariMNIST2018 forward. B=4096, T=15, HW=784, F1=500, F3=10.
// Output layout (float32, concatenated):
//   spk1 [4096*15*500] @ 0
//   thr1 [4096*15*500] @ 30720000
//   pot3 [4096*15*10]  @ 61440000
//   cls  [4096]        @ 62054400
//
// R17 = R16 (177.2us) with ONE micro-change: the in-loop t0 dword load is
// 2-deep prefetched (issue ks+2's dword at iter ks, rebuild ks+1's dword
// loaded last iter) so the L2 load is fully off the critical path.
// Everything else byte-identical to R16.

typedef _Float16     f16x8 __attribute__((ext_vector_type(8)));
typedef float        f32x4 __attribute__((ext_vector_type(4)));
typedef unsigned int u32x4 __attribute__((ext_vector_type(4)));

typedef __attribute__((address_space(3))) char        lds_char_t;
typedef const __attribute__((address_space(1))) char  gbl_char_t;

#define GLL16(gsrc, ldst) \
  __builtin_amdgcn_global_load_lds((gbl_char_t*)(gsrc), (lds_char_t*)(ldst), 16, 0, 0)

#define CONV1_T 26.3424f
#define KDIM 784
#define F1   500

__global__ __launch_bounds__(256)
void k_zero(float* __restrict__ p, int n)
{
    const int i = blockIdx.x * 256 + threadIdx.x;
    if (i < n) p[i] = 0.f;
}

// rebuild 8 spike halfs from a t0 nibble dword: v[e] = (nib_e <= t)
__device__ __forceinline__
f16x8 rebuild_a(unsigned int d, int t)
{
    u32x4 br;
    #pragma unroll
    for (int h = 0; h < 4; ++h) {
        const unsigned int n0 = (d >> (8 * h))     & 15u;
        const unsigned int n1 = (d >> (8 * h + 4)) & 15u;
        br[h] = (n0 <= (unsigned)t ? 0x3C00u     : 0u)
              | (n1 <= (unsigned)t ? 0x3C000000u : 0u);
    }
    return __builtin_bit_cast(f16x8, br);
}

// ------------------------------------------------------------------
// k_prep (R3/R11/R12): split w1 [500x784] fp32 into f16 hi/lo, laid out
// exactly as the conv1 LDS tile bytes (GLL16-linear). Tile (nb*25+ks) is
// 32768 B: byte b -> part=b>>14 (0=hi,1=lo), nl=(b&16383)>>6,
// slot=(b>>4)&3, e=(b>>1)&7, k-chunk j = slot^((nl>>1)&3).
// ------------------------------------------------------------------
__global__ __launch_bounds__(256)
void k_prep(const float* __restrict__ w1, float* __restrict__ scratch)
{
    const int c = blockIdx.x * 256 + threadIdx.x;   // one 16B chunk each
    const int tile  = c >> 11;
    const int chunk = c & 2047;
    const int nb   = tile / 25;
    const int ks   = tile % 25;
    const int part = chunk >> 10;
    const int nl   = (chunk & 1023) >> 2;
    const int slot = chunk & 3;
    const int j    = slot ^ ((nl >> 1) & 3);
    const int k0   = ks * 32 + j * 8;
    const int ng   = nb * 256 + nl;

    f16x8 v;
    #pragma unroll
    for (int e = 0; e < 8; ++e) {
        const int kk = k0 + e;
        const float val = (ng < F1 && kk < KDIM) ? w1[ng * KDIM + kk] : 0.f;
        const _Float16 h = (_Float16)val;
        v[e] = part ? (_Float16)(val - (float)h) : h;
    }
    *(f16x8*)((char*)scratch + (size_t)c * 16) = v;
}

// ------------------------------------------------------------------
// k_conv1_t0: phase-0 t0 prologue (per-block, race-free-by-value), R15
// main loop with 2-deep t0 prefetch, fused conv3 epilogue.
// Tile BM=128, BN=256 (nb half), BK=32. 512 threads = 8 waves (2M x 4N).
// ------------------------------------------------------------------
__global__ __launch_bounds__(512, 4)
void k_conv1_t0(const float* __restrict__ inp,
                unsigned int* __restrict__ t0nib,
                const float* __restrict__ bsplit,
                const float* __restrict__ w3,
                float* __restrict__ spk1, float* __restrict__ thr1,
                float* __restrict__ pot3)
{
    __shared__ char smem[81920];
    _Float16* sAh = (_Float16*)smem;              // 2 x 4096 halfs
    _Float16* sBh = (_Float16*)(smem + 16384);    // 2 x 16384 halfs

    const int tid  = threadIdx.x;
    const int lane = tid & 63;
    const int wid  = tid >> 6;     // 0..7
    const int wm   = wid >> 2;     // 0..1 (M)
    const int wn   = wid & 3;      // 0..3 (N)
    const int lr   = lane & 15;
    const int kg   = lane >> 4;

    // XCD pairing: bx and bx^8 share the same A tile on the same XCD.
    const int bx   = blockIdx.x;                    // 0..959
    const int nb   = (bx >> 3) & 1;
    const int mblk = ((bx >> 4) << 3) | (bx & 7);   // 0..479
    const long long rowBase = (long long)mblk * 128;

    // ---- phase 0: compute this block's t0 rows (k_t0 arithmetic verbatim)
    {
        const int bStart = (int)(rowBase / 15);
        const int bEnd   = (int)((rowBase + 127) / 15);
        const int nWork  = (bEnd - bStart + 1) * 100;   // <= 1000
        for (int w = tid; w < nWork; w += 512) {
            const int b  = bStart + w / 100;
            const int p8 = w % 100;
            unsigned int d;
            if (p8 >= 98) {
                d = 0xFFFFFFFFu;
            } else {
                const float* base = inp + (size_t)b * 11760 + p8 * 8;
                float cnt[8];
                #pragma unroll
                for (int e = 0; e < 8; ++e) cnt[e] = 0.f;
                #pragma unroll
                for (int t = 0; t < 15; ++t) {
                    const f32x4 v0 = *(const f32x4*)(base + t * 784);
                    const f32x4 v1 = *(const f32x4*)(base + t * 784 + 4);
                    #pragma unroll
                    for (int e = 0; e < 4; ++e) { cnt[e] += v0[e]; cnt[e + 4] += v1[e]; }
                }
                d = 0;
                #pragma unroll
                for (int e = 0; e < 8; ++e) {
                    const unsigned int t0 = 15u - (unsigned int)cnt[e];   // 0..14
                    d |= (t0 & 15u) << (4 * e);
                }
            }
            t0nib[b * 100 + p8] = d;
        }
    }
    __syncthreads();

    // A staging role: thread -> (row sm, 8-wide k-chunk sk8)
    const int sm  = tid >> 2;      // 0..127
    const int sk8 = tid & 3;
    const int aWr = sm * 32 + (sk8 ^ ((sm >> 1) & 3)) * 8;
    const long long am = rowBase + sm;
    const int at = (int)(am % 15);
    const unsigned char* atp = (const unsigned char*)t0nib
                             + (am / 15) * 400 + sk8 * 4;          // + ks*16

    // B: global_load_lds source (lane's 16B baked in); 4 x 1KB per wave
    const char* gBsrc = (const char*)bsplit + (size_t)(nb * 25) * 32768
                      + (size_t)wid * 4096 + (size_t)lane * 16;

    f32x4 acc[4][4];
    #pragma unroll
    for (int i = 0; i < 4; ++i)
        #pragma unroll
        for (int j = 0; j < 4; ++j) acc[i][j] = {0.f, 0.f, 0.f, 0.f};

    int aOff[4], bOff[4];
    #pragma unroll
    for (int fm = 0; fm < 4; ++fm) {
        const int r = wm * 64 + fm * 16 + lr;
        aOff[fm] = r * 32 + (kg ^ ((r >> 1) & 3)) * 8;
    }
    #pragma unroll
    for (int fn = 0; fn < 4; ++fn) {
        const int n = wn * 64 + fn * 16 + lr;
        bOff[fn] = n * 32 + (kg ^ ((n >> 1) & 3)) * 8;
    }

    // ---- prologue: stage ks=0 into buffer 0; preload t0 dword for ks=1
    unsigned int dN1;
    {
        #pragma unroll
        for (int i = 0; i < 4; ++i)
            GLL16(gBsrc + i * 1024,
                  (lds_char_t*)smem + 16384 + (size_t)wid * 4096 + i * 1024);
        const unsigned int d = *(const unsigned int*)(atp);
        *(f16x8*)&sAh[aWr] = rebuild_a(d, at);
        dN1 = *(const unsigned int*)(atp + 16);   // for ks=1
    }
    __syncthreads();

    for (int ks = 0; ks < 25; ++ks) {
        const int  cur = ks & 1;
        const bool pf  = (ks + 1 < 25);

        // ---- issue prefetches: B(ks+1) via GLL16; t0 dword for ks+2
        unsigned int dN2 = 0;
        if (ks + 2 < 25)
            dN2 = *(const unsigned int*)(atp + (ks + 2) * 16);
        if (pf) {
            const char*  src = gBsrc + (size_t)(ks + 1) * 32768;
            lds_char_t*  dst = (lds_char_t*)smem + 16384 + (size_t)(cur ^ 1) * 32768
                             + (size_t)wid * 4096;
            #pragma unroll
            for (int i = 0; i < 4; ++i)
                GLL16(src + i * 1024, dst + i * 1024);
        }

        // ---- compute tile ks from buffer cur
        const _Float16* sAc = sAh + (size_t)cur * 4096;
        const _Float16* sBc = sBh + (size_t)cur * 16384;
        const f16x8 a0 = *(const f16x8*)&sAc[aOff[0]];
        const f16x8 a1 = *(const f16x8*)&sAc[aOff[1]];
        const f16x8 a2 = *(const f16x8*)&sAc[aOff[2]];
        const f16x8 a3 = *(const f16x8*)&sAc[aOff[3]];
        #pragma unroll
        for (int fn = 0; fn < 4; ++fn) {
            const f16x8 bh = *(const f16x8*)&sBc[bOff[fn]];
            const f16x8 bl = *(const f16x8*)&sBc[8192 + bOff[fn]];
            acc[0][fn] = __builtin_amdgcn_mfma_f32_16x16x32_f16(a0, bh, acc[0][fn], 0, 0, 0);
            acc[0][fn] = __builtin_amdgcn_mfma_f32_16x16x32_f16(a0, bl, acc[0][fn], 0, 0, 0);
            acc[1][fn] = __builtin_amdgcn_mfma_f32_16x16x32_f16(a1, bh, acc[1][fn], 0, 0, 0);
            acc[1][fn] = __builtin_amdgcn_mfma_f32_16x16x32_f16(a1, bl, acc[1][fn], 0, 0, 0);
            acc[2][fn] = __builtin_amdgcn_mfma_f32_16x16x32_f16(a2, bh, acc[2][fn], 0, 0, 0);
            acc[2][fn] = __builtin_amdgcn_mfma_f32_16x16x32_f16(a2, bl, acc[2][fn], 0, 0, 0);
            acc[3][fn] = __builtin_amdgcn_mfma_f32_16x16x32_f16(a3, bh, acc[3][fn], 0, 0, 0);
            acc[3][fn] = __builtin_amdgcn_mfma_f32_16x16x32_f16(a3, bl, acc[3][fn], 0, 0, 0);
        }

        // ---- finish A prefetch: rebuild (from pre-loaded dword) + ds_write
        if (pf)
            *(f16x8*)&sAh[(size_t)(cur ^ 1) * 4096 + aWr] = rebuild_a(dN1, at);
        dN1 = dN2;
        __syncthreads();
    }

    // ---- epilogue part 1: fire, global stores, spike tile -> swizzled LDS.
    // C/D layout: col = lane&15, row = (lane>>4)*4 + r.
    // Spike LDS: [128][256] f16, byte = rowL*512 + colL*2, ^= (rowL&7)<<4.
    #pragma unroll
    for (int fm = 0; fm < 4; ++fm) {
        #pragma unroll
        for (int fn = 0; fn < 4; ++fn) {
            const int colL = wn * 64 + fn * 16 + lr;
            const int ng   = nb * 256 + colL;
            #pragma unroll
            for (int r = 0; r < 4; ++r) {
                const int rowL = wm * 64 + fm * 16 + kg * 4 + r;
                const long long m = rowBase + rowL;
                const float p   = acc[fm][fn][r];
                const bool fire = (p >= CONV1_T);
                int sbyte = rowL * 512 + colL * 2;
                sbyte ^= ((rowL & 7) << 4);
                *(_Float16*)(smem + sbyte) = fire ? (_Float16)1.f : (_Float16)0.f;
                if (ng < F1) {
                    thr1[m * F1 + ng] = fire ? p : 0.f;
                    spk1[m * F1 + ng] = fire ? 1.f : 0.f;
                }
            }
        }
    }
    __syncthreads();

    // ---- epilogue part 2: conv3 partial = spikes[128x256] x w3^T[256x10].
    {
        f32x4 acc3 = {0.f, 0.f, 0.f, 0.f};
        const int mrow = wid * 16 + lr;
        #pragma unroll
        for (int kc = 0; kc < 8; ++kc) {
            int abyte = mrow * 512 + (kc * 32 + kg * 8) * 2;
            abyte ^= ((mrow & 7) << 4);
            const f16x8 a3 = *(const f16x8*)(smem + abyte);
            f16x8 b3;
            const int f0 = nb * 256 + kc * 32 + kg * 8;
            if (lr < 10) {
                const float* wr = w3 + lr * F1 + f0;
                #pragma unroll
                for (int e = 0; e < 8; ++e)
                    b3[e] = (f0 + e < F1) ? (_Float16)wr[e] : (_Float16)0.f;
            } else {
                #pragma unroll
                for (int e = 0; e < 8; ++e) b3[e] = (_Float16)0.f;
            }
            acc3 = __builtin_amdgcn_mfma_f32_16x16x32_f16(a3, b3, acc3, 0, 0, 0);
        }
        if (lr < 10) {
            #pragma unroll
            for (int r = 0; r < 4; ++r) {
                const long long m = rowBase + wid * 16 + kg * 4 + r;
                atomicAdd(&pot3[m * 10 + lr], acc3[r]);
            }
        }
    }
}

// ------------------------------------------------------------------
// k_conv1_f32 (R11 verbatim; fallback when d_ws too small).
// ------------------------------------------------------------------
__global__ __launch_bounds__(512, 4)
void k_conv1_f32(const float* __restrict__ inp, const float* __restrict__ bsplit,
                 float* __restrict__ spk1, float* __restrict__ thr1)
{
    __shared__ _Float16 sA[2][128 * 32];
    __shared__ _Float16 sB[2][2 * 256 * 32];

    const int tid  = threadIdx.x;
    const int lane = tid & 63;
    const int wid  = tid >> 6;
    const int wm   = wid >> 2;
    const int wn   = wid & 3;
    const int lr   = lane & 15;
    const int kg   = lane >> 4;

    const int bx   = blockIdx.x;
    const int nb   = (bx >> 3) & 1;
    const int mblk = ((bx >> 4) << 3) | (bx & 7);
    const long long rowBase = (long long)mblk * 128;

    const int sm  = tid >> 2;
    const int sk8 = tid & 3;
    const int aWr = sm * 32 + (sk8 ^ ((sm >> 1) & 3)) * 8;
    const float* gA = inp + (rowBase + sm) * KDIM + sk8 * 8;

    const char* gBsrc = (const char*)bsplit + (size_t)(nb * 25) * 32768
                      + (size_t)wid * 4096 + (size_t)lane * 16;

    f32x4 acc[4][4];
    #pragma unroll
    for (int i = 0; i < 4; ++i)
        #pragma unroll
        for (int j = 0; j < 4; ++j) acc[i][j] = {0.f, 0.f, 0.f, 0.f};

    int aOff[4], bOff[4];
    #pragma unroll
    for (int fm = 0; fm < 4; ++fm) {
        const int r = wm * 64 + fm * 16 + lr;
        aOff[fm] = r * 32 + (kg ^ ((r >> 1) & 3)) * 8;
    }
    #pragma unroll
    for (int fn = 0; fn < 4; ++fn) {
        const int n = wn * 64 + fn * 16 + lr;
        bOff[fn] = n * 32 + (kg ^ ((n >> 1) & 3)) * 8;
    }

    {
        const f32x4 x0 = *(const f32x4*)(gA);
        const f32x4 x1 = *(const f32x4*)(gA + 4);
        #pragma unroll
        for (int i = 0; i < 4; ++i)
            GLL16(gBsrc + i * 1024, (lds_char_t*)&sB[0][0] + wid * 4096 + i * 1024);
        f16x8 v;
        #pragma unroll
        for (int e = 0; e < 4; ++e) { v[e] = (_Float16)x0[e]; v[e + 4] = (_Float16)x1[e]; }
        *(f16x8*)&sA[0][aWr] = v;
    }
    __syncthreads();

    for (int ks = 0; ks < 25; ++ks) {
        const int  cur = ks & 1;
        const bool pf  = (ks + 1 < 25);

        f32x4 x0 = {0.f, 0.f, 0.f, 0.f}, x1 = {0.f, 0.f, 0.f, 0.f};
        bool av = false;
        if (pf) {
            const int k0 = (ks + 1) * 32 + sk8 * 8;
            av = (k0 + 8 <= KDIM);
            if (av) {
                x0 = *(const f32x4*)(gA + (ks + 1) * 32);
                x1 = *(const f32x4*)(gA + (ks + 1) * 32 + 4);
            }
            const char*  src = gBsrc + (size_t)(ks + 1) * 32768;
            lds_char_t*  dst = (lds_char_t*)&sB[cur ^ 1][0] + wid * 4096;
            #pragma unroll
            for (int i = 0; i < 4; ++i)
                GLL16(src + i * 1024, dst + i * 1024);
        }

        const f16x8 a0 = *(const f16x8*)&sA[cur][aOff[0]];
        const f16x8 a1 = *(const f16x8*)&sA[cur][aOff[1]];
        const f16x8 a2 = *(const f16x8*)&sA[cur][aOff[2]];
        const f16x8 a3 = *(const f16x8*)&sA[cur][aOff[3]];
        #pragma unroll
        for (int fn = 0; fn < 4; ++fn) {
            const f16x8 bh = *(const f16x8*)&sB[cur][bOff[fn]];
            const f16x8 bl = *(const f16x8*)&sB[cur][8192 + bOff[fn]];
            acc[0][fn] = __builtin_amdgcn_mfma_f32_16x16x32_f16(a0, bh, acc[0][fn], 0, 0, 0);
            acc[0][fn] = __builtin_amdgcn_mfma_f32_16x16x32_f16(a0, bl, acc[0][fn], 0, 0, 0);
            acc[1][fn] = __builtin_amdgcn_mfma_f32_16x16x32_f16(a1, bh, acc[1][fn], 0, 0, 0);
            acc[1][fn] = __builtin_amdgcn_mfma_f32_16x16x32_f16(a1, bl, acc[1][fn], 0, 0, 0);
            acc[2][fn] = __builtin_amdgcn_mfma_f32_16x16x32_f16(a2, bh, acc[2][fn], 0, 0, 0);
            acc[2][fn] = __builtin_amdgcn_mfma_f32_16x16x32_f16(a2, bl, acc[2][fn], 0, 0, 0);
            acc[3][fn] = __builtin_amdgcn_mfma_f32_16x16x32_f16(a3, bh, acc[3][fn], 0, 0, 0);
            acc[3][fn] = __builtin_amdgcn_mfma_f32_16x16x32_f16(a3, bl, acc[3][fn], 0, 0, 0);
        }

        if (pf) {
            f16x8 v;
            #pragma unroll
            for (int e = 0; e < 4; ++e) {
                v[e]     = av ? (_Float16)x0[e] : (_Float16)0.f;
                v[e + 4] = av ? (_Float16)x1[e] : (_Float16)0.f;
            }
            *(f16x8*)&sA[cur ^ 1][aWr] = v;
        }
        __syncthreads();
    }

    #pragma unroll
    for (int fm = 0; fm < 4; ++fm) {
        #pragma unroll
        for (int fn = 0; fn < 4; ++fn) {
            const int ng = nb * 256 + wn * 64 + fn * 16 + lr;
            if (ng < F1) {
                #pragma unroll
                for (int r = 0; r < 4; ++r) {
                    const long long m = rowBase + wm * 64 + fm * 16 + kg * 4 + r;
                    const float p   = acc[fm][fn][r];
                    const bool fire = (p >= CONV1_T);
                    thr1[m * F1 + ng] = fire ? p : 0.f;
                    spk1[m * F1 + ng] = fire ? 1.f : 0.f;
                }
            }
        }
    }
}

// ------------------------------------------------------------------
// k_conv3 (R5-verified; fallback path only): pot3 via 16x16x32 f16 MFMA.
// ------------------------------------------------------------------
__global__ __launch_bounds__(256)
void k_conv3(const float* __restrict__ spk1, const float* __restrict__ w3,
             float* __restrict__ pot3)
{
    const int tid  = threadIdx.x;
    const int lane = tid & 63;
    const int wid  = tid >> 6;
    const int gw   = blockIdx.x * 4 + wid;    // 0..3839
    const long long row0 = (long long)gw * 16;
    const int lr = lane & 15;
    const int kg = lane >> 4;
    const int n  = (lr < 10) ? lr : 0;

    const float* arow = spk1 + (row0 + lr) * F1;
    const float* brow = w3 + (size_t)n * F1;

    f32x4 acc = {0.f, 0.f, 0.f, 0.f};
    #pragma unroll
    for (int ks = 0; ks < 16; ++ks) {
        const int k0 = ks * 32 + kg * 8;
        f16x8 a, b;
        if (k0 + 8 <= F1) {
            const f32x4 a0 = *(const f32x4*)(arow + k0);
            const f32x4 a1 = *(const f32x4*)(arow + k0 + 4);
            const f32x4 b0 = *(const f32x4*)(brow + k0);
            const f32x4 b1 = *(const f32x4*)(brow + k0 + 4);
            #pragma unroll
            for (int e = 0; e < 4; ++e) {
                a[e] = (_Float16)a0[e]; a[e + 4] = (_Float16)a1[e];
                b[e] = (_Float16)b0[e]; b[e + 4] = (_Float16)b1[e];
            }
        } else {
            #pragma unroll
            for (int e = 0; e < 8; ++e) {
                const int k = k0 + e;
                a[e] = (k < F1) ? (_Float16)arow[k] : (_Float16)0.f;
                b[e] = (k < F1) ? (_Float16)brow[k] : (_Float16)0.f;
            }
        }
        acc = __builtin_amdgcn_mfma_f32_16x16x32_f16(a, b, acc, 0, 0, 0);
    }
    if (lr < 10) {
        #pragma unroll
        for (int r = 0; r < 4; ++r) {
            const long long m = row0 + kg * 4 + r;
            pot3[m * 10 + lr] = acc[r];
        }
    }
}

// ------------------------------------------------------------------
// k_winner: winner-take-all per batch, faithful to reference algebra.
// ------------------------------------------------------------------
__global__ __launch_bounds__(256)
void k_winner(const float* __restrict__ pot3, float* __restrict__ outCls, int nB)
{
    const int b = blockIdx.x * 256 + threadIdx.x;
    if (b >= nB) return;
    const float* p = pot3 + (long long)b * 150 + 140;   // t = 14 row

    float pv[10], s[10];
    float mv = 0.f;
    #pragma unroll
    for (int g = 0; g < 10; ++g) {
        const float v = p[g];
        pv[g] = v;
        s[g]  = (v > 0.f) ? 1.f : ((v < 0.f) ? -1.f : 0.f);
        mv = fmaxf(mv, s[g] * v);
    }
    const float vbig = mv * 15.f;
    float bm = -INFINITY; int bi = 0;
    #pragma unroll
    for (int g = 0; g < 10; ++g) {
        const float tot = s[g] * pv[g] + s[g] * vbig;
        if (tot > bm) { bm = tot; bi = g; }
    }
    outCls[b] = (bm != 0.f) ? (float)bi : -1.f;
}

// ------------------------------------------------------------------
extern "C" void kernel_launch(void* const* d_in, const int* in_sizes, int n_in,
                              void* d_out, int out_size, void* d_ws, size_t ws_size,
                              hipStream_t stream)
{
    const float* inp = (const float*)d_in[0];
    const float* w1  = (const float*)d_in[1];
    const float* w3  = (const float*)d_in[2];

    float* out  = (float*)d_out;
    float* spk1 = out;
    float* thr1 = out + 30720000LL;
    float* pot3 = out + 61440000LL;
    float* cls  = out + 62054400LL;

    if (ws_size >= 3276800) {
        // fused path: w1split (1638400 B) + t0nib (1638400 B) in d_ws;
        // t0nib is computed by conv1's own prologue (no separate pass).
        float*        w1split = (float*)d_ws;
        unsigned int* t0nib   = (unsigned int*)((char*)d_ws + 1638400);
        k_prep    <<<400,  256, 0, stream>>>(w1, w1split);
        k_zero    <<<2400, 256, 0, stream>>>(pot3, 614400);
        k_conv1_t0<<<960,  512, 0, stream>>>(inp, t0nib, w1split, w3,
                                             spk1, thr1, pot3);
    } else {
        // fallback: R11-exact (scratch borrows pot3; conv3 separate)
        float* scratch = pot3;
        k_prep     <<<400, 256, 0, stream>>>(w1, scratch);
        k_conv1_f32<<<960, 512, 0, stream>>>(inp, scratch, spk1, thr1);
        k_conv3    <<<960, 256, 0, stream>>>(spk1, w3, pot3);
    }
    k_winner<<<16, 256, 0, stream>>>(pot3, cls, 4096);
}